// Round 1
// baseline (340.970 us; speedup 1.0000x reference)
//
#include <hip/hip_runtime.h>
#include <hip/hip_bf16.h>

// ---------------------------------------------------------------------------
// GCN: 3 x (linear -> segment-mean over in-edges -> [relu]) -> log_softmax
// Strategy: build CSR (edges grouped by dst) once per call, then
//   gemm (LDS-tiled fp32) -> wave-per-node gather-mean (no float atomics).
// ---------------------------------------------------------------------------

__global__ void hist_kernel(const int* __restrict__ col, int* __restrict__ cnt, int E) {
    int e = blockIdx.x * blockDim.x + threadIdx.x;
    if (e < E) atomicAdd(&cnt[col[e]], 1);
}

__global__ void scan_partial(const int* __restrict__ cnt, int* __restrict__ bsum, int n) {
    __shared__ int lds[256];
    int i = blockIdx.x * 256 + threadIdx.x;
    int v = (i < n) ? cnt[i] : 0;
    lds[threadIdx.x] = v;
    __syncthreads();
    for (int s = 128; s > 0; s >>= 1) {
        if (threadIdx.x < s) lds[threadIdx.x] += lds[threadIdx.x + s];
        __syncthreads();
    }
    if (threadIdx.x == 0) bsum[blockIdx.x] = lds[0];
}

// single block; nb <= 256
__global__ void scan_bsums(int* __restrict__ bsum, int nb) {
    __shared__ int lds[256];
    int t = threadIdx.x;
    int v = (t < nb) ? bsum[t] : 0;
    lds[t] = v;
    __syncthreads();
    for (int off = 1; off < 256; off <<= 1) {
        int u = (t >= off) ? lds[t - off] : 0;
        __syncthreads();
        lds[t] += u;
        __syncthreads();
    }
    if (t < nb) bsum[t] = lds[t] - v;  // exclusive
}

__global__ void scan_final(const int* __restrict__ cnt, const int* __restrict__ bsum,
                           int* __restrict__ start, int* __restrict__ cursor, int n) {
    __shared__ int lds[256];
    int t = threadIdx.x;
    int i = blockIdx.x * 256 + t;
    int v = (i < n) ? cnt[i] : 0;
    lds[t] = v;
    __syncthreads();
    for (int off = 1; off < 256; off <<= 1) {
        int u = (t >= off) ? lds[t - off] : 0;
        __syncthreads();
        lds[t] += u;
        __syncthreads();
    }
    if (i < n) {
        int excl = lds[t] - v + bsum[blockIdx.x];
        start[i]  = excl;
        cursor[i] = excl;
    }
}

__global__ void scatter_kernel(const int* __restrict__ row, const int* __restrict__ col,
                               int* __restrict__ cursor, int* __restrict__ srclist, int E) {
    int e = blockIdx.x * blockDim.x + threadIdx.x;
    if (e < E) {
        int p = atomicAdd(&cursor[col[e]], 1);
        srclist[p] = row[e];
    }
}

// ---------------------------------------------------------------------------
// GEMM: Y[n x OUT] = X[n x 128] @ W[128 x OUT] + bias.  fp32 vector ALU.
// Block: 256 threads = 16x16; 64 rows per block; K chunked by 32.
// Thread computes 4 rows x (OUT/16) cols.
// ---------------------------------------------------------------------------
template <int OUT>
__global__ __launch_bounds__(256) void gemm_kernel(
    const float* __restrict__ X, const float* __restrict__ W,
    const float* __restrict__ bias, float* __restrict__ Y, int n) {
    constexpr int NCG  = OUT / 64;   // float4 col-groups per thread (1 or 2)
    constexpr int WPAD = OUT + 8;    // keep rows 16B-aligned, break bank patterns
    __shared__ float xs[64][36];     // 36 floats/row: 16B-aligned, conflict-free reads
    __shared__ float wsh[32][WPAD];

    const int t  = threadIdx.x;
    const int tr = t >> 4;   // 0..15
    const int tc = t & 15;   // 0..15
    const int r0 = blockIdx.x * 64;

    float acc[4][NCG * 4];
#pragma unroll
    for (int i = 0; i < 4; ++i)
#pragma unroll
        for (int j = 0; j < NCG * 4; ++j) acc[i][j] = 0.f;

    for (int kc = 0; kc < 4; ++kc) {
        // stage X tile: 64 rows x 32 k  (512 float4, 2 per thread)
#pragma unroll
        for (int q = 0; q < 2; ++q) {
            int f  = t + q * 256;
            int r  = f >> 3;
            int k4 = f & 7;
            int gr = r0 + r;
            if (gr >= n) gr = n - 1;
            float4 v = *(const float4*)&X[gr * 128 + kc * 32 + k4 * 4];
            *(float4*)&xs[r][k4 * 4] = v;
        }
        // stage W tile: 32 k x OUT cols
#pragma unroll
        for (int q = 0; q < NCG * 2; ++q) {
            int f  = t + q * 256;
            int kk = f / (OUT / 4);
            int c4 = f % (OUT / 4);
            float4 v = *(const float4*)&W[(kc * 32 + kk) * OUT + c4 * 4];
            *(float4*)&wsh[kk][c4 * 4] = v;
        }
        __syncthreads();

#pragma unroll
        for (int k4 = 0; k4 < 8; ++k4) {
            float4 xv[4];
#pragma unroll
            for (int i = 0; i < 4; ++i)
                xv[i] = *(const float4*)&xs[tr * 4 + i][k4 * 4];
#pragma unroll
            for (int kk = 0; kk < 4; ++kk) {
#pragma unroll
                for (int g = 0; g < NCG; ++g) {
                    float4 wv = *(const float4*)&wsh[k4 * 4 + kk][g * 64 + tc * 4];
#pragma unroll
                    for (int i = 0; i < 4; ++i) {
                        float xk = ((const float*)&xv[i])[kk];
                        acc[i][g * 4 + 0] += xk * wv.x;
                        acc[i][g * 4 + 1] += xk * wv.y;
                        acc[i][g * 4 + 2] += xk * wv.z;
                        acc[i][g * 4 + 3] += xk * wv.w;
                    }
                }
            }
        }
        __syncthreads();
    }

#pragma unroll
    for (int g = 0; g < NCG; ++g) {
        float4 bv = *(const float4*)&bias[g * 64 + tc * 4];
#pragma unroll
        for (int i = 0; i < 4; ++i) {
            int r = r0 + tr * 4 + i;
            if (r < n) {
                float4 o;
                o.x = acc[i][g * 4 + 0] + bv.x;
                o.y = acc[i][g * 4 + 1] + bv.y;
                o.z = acc[i][g * 4 + 2] + bv.z;
                o.w = acc[i][g * 4 + 3] + bv.w;
                *(float4*)&Y[r * OUT + g * 64 + tc * 4] = o;
            }
        }
    }
}

// ---------------------------------------------------------------------------
// Aggregation: one wave (64 lanes) per destination node.
// D=128: each lane owns a float2 slice (512B coalesced row reads).
// ---------------------------------------------------------------------------
template <bool RELU>
__global__ void agg128_kernel(const float* __restrict__ h, const int* __restrict__ start,
                              const int* __restrict__ cnt, const int* __restrict__ srclist,
                              float* __restrict__ out, int n) {
    int wid  = (blockIdx.x * blockDim.x + threadIdx.x) >> 6;
    int lane = threadIdx.x & 63;
    if (wid >= n) return;
    int s0 = start[wid];
    int c  = cnt[wid];
    float ax = 0.f, ay = 0.f;
    int e = 0;
    for (; e + 1 < c; e += 2) {  // 2-deep to keep two gathers in flight
        int s1 = srclist[s0 + e];
        int s2 = srclist[s0 + e + 1];
        float2 v1 = *(const float2*)&h[s1 * 128 + lane * 2];
        float2 v2 = *(const float2*)&h[s2 * 128 + lane * 2];
        ax += v1.x + v2.x;
        ay += v1.y + v2.y;
    }
    if (e < c) {
        int s1 = srclist[s0 + e];
        float2 v1 = *(const float2*)&h[s1 * 128 + lane * 2];
        ax += v1.x; ay += v1.y;
    }
    float rx, ry;
    if (c > 0) {
        float inv = 1.f / (float)c;
        rx = ax * inv; ry = ay * inv;
    } else {
        float2 v = *(const float2*)&h[wid * 128 + lane * 2];
        rx = v.x; ry = v.y;
    }
    if (RELU) { rx = fmaxf(rx, 0.f); ry = fmaxf(ry, 0.f); }
    float2 o; o.x = rx; o.y = ry;
    *(float2*)&out[wid * 128 + lane * 2] = o;
}

// D=64 final layer: lane owns 1 float; fused log_softmax via wave shuffles.
__global__ void agg64_logsoftmax_kernel(const float* __restrict__ h, const int* __restrict__ start,
                                        const int* __restrict__ cnt, const int* __restrict__ srclist,
                                        float* __restrict__ out, int n) {
    int wid  = (blockIdx.x * blockDim.x + threadIdx.x) >> 6;
    int lane = threadIdx.x & 63;
    if (wid >= n) return;
    int s0 = start[wid];
    int c  = cnt[wid];
    float a = 0.f;
    int e = 0;
    for (; e + 1 < c; e += 2) {
        int s1 = srclist[s0 + e];
        int s2 = srclist[s0 + e + 1];
        a += h[s1 * 64 + lane] + h[s2 * 64 + lane];
    }
    if (e < c) a += h[srclist[s0 + e] * 64 + lane];
    float v = (c > 0) ? a / (float)c : h[wid * 64 + lane];

    float m = v;
#pragma unroll
    for (int off = 32; off > 0; off >>= 1) m = fmaxf(m, __shfl_xor(m, off));
    float ex = __expf(v - m);
    float s = ex;
#pragma unroll
    for (int off = 32; off > 0; off >>= 1) s += __shfl_xor(s, off);
    out[wid * 64 + lane] = v - m - __logf(s);
}

// ---------------------------------------------------------------------------
extern "C" void kernel_launch(void* const* d_in, const int* in_sizes, int n_in,
                              void* d_out, int out_size, void* d_ws, size_t ws_size,
                              hipStream_t stream) {
    const float* x  = (const float*)d_in[0];
    const int*   ei = (const int*)d_in[1];   // int32 on device (JAX x64 disabled)
    const float* W1 = (const float*)d_in[2];
    const float* b1 = (const float*)d_in[3];
    const float* W2 = (const float*)d_in[4];
    const float* b2 = (const float*)d_in[5];
    const float* W3 = (const float*)d_in[6];
    const float* b3 = (const float*)d_in[7];
    float* out = (float*)d_out;

    const int n = in_sizes[0] / 128;
    const int E = in_sizes[1] / 2;
    const int* row = ei;        // edge_index[0]
    const int* col = ei + E;    // edge_index[1]

    // workspace carve-up (256B-aligned): ~55 MB total
    char* ws = (char*)d_ws;
    size_t off = 0;
    auto carve = [&](size_t bytes) {
        char* p = ws + off;
        off = (off + bytes + 255) & ~(size_t)255;
        return p;
    };
    float* bufA    = (float*)carve((size_t)n * 128 * sizeof(float));
    float* bufB    = (float*)carve((size_t)n * 128 * sizeof(float));
    int*   cnt     = (int*)carve((size_t)n * sizeof(int));
    int*   start   = (int*)carve((size_t)n * sizeof(int));
    int*   cursor  = (int*)carve((size_t)n * sizeof(int));
    int*   srclist = (int*)carve((size_t)E * sizeof(int));
    int*   bsum    = (int*)carve(1024);

    // --- CSR build (edges grouped by destination) ---
    hipMemsetAsync(cnt, 0, (size_t)n * sizeof(int), stream);
    int egrid = (E + 255) / 256;
    int nb    = (n + 255) / 256;   // 196 <= 256 (scan_bsums capacity)
    hist_kernel<<<egrid, 256, 0, stream>>>(col, cnt, E);
    scan_partial<<<nb, 256, 0, stream>>>(cnt, bsum, n);
    scan_bsums<<<1, 256, 0, stream>>>(bsum, nb);
    scan_final<<<nb, 256, 0, stream>>>(cnt, bsum, start, cursor, n);
    scatter_kernel<<<egrid, 256, 0, stream>>>(row, col, cursor, srclist, E);

    // --- 3 GCN layers ---
    int ggrid = (n + 63) / 64;
    int agrid = (n + 3) / 4;   // 4 waves/block, 1 node per wave
    gemm_kernel<128><<<ggrid, 256, 0, stream>>>(x, W1, b1, bufA, n);
    agg128_kernel<true><<<agrid, 256, 0, stream>>>(bufA, start, cnt, srclist, bufB, n);
    gemm_kernel<128><<<ggrid, 256, 0, stream>>>(bufB, W2, b2, bufA, n);
    agg128_kernel<true><<<agrid, 256, 0, stream>>>(bufA, start, cnt, srclist, bufB, n);
    gemm_kernel<64><<<ggrid, 256, 0, stream>>>(bufB, W3, b3, bufA, n);
    agg64_logsoftmax_kernel<<<agrid, 256, 0, stream>>>(bufA, start, cnt, srclist, out, n);
}

// Round 2
// 308.513 us; speedup vs baseline: 1.1052x; 1.1052x over previous
//
#include <hip/hip_runtime.h>
#include <hip/hip_bf16.h>

// ---------------------------------------------------------------------------
// GCN: 3 x (linear -> segment-mean over in-edges -> [relu]) -> log_softmax
// CSR build (group edges by dst) once per call, then
//   gemm (LDS-tiled fp32) -> wave-per-node gather-mean.
// R2: aggregation gathers are latency-bound (VALUBusy 17%, 0 conflicts,
//     3.4 TB/s). Prefetch 64 indices via one lane-parallel load + __shfl
//     broadcast, and issue 8 independent gathers per step (8-deep MLP).
// ---------------------------------------------------------------------------

__global__ void hist_kernel(const int* __restrict__ col, int* __restrict__ cnt, int E) {
    int e = blockIdx.x * blockDim.x + threadIdx.x;
    if (e < E) atomicAdd(&cnt[col[e]], 1);
}

__global__ void scan_partial(const int* __restrict__ cnt, int* __restrict__ bsum, int n) {
    __shared__ int lds[256];
    int i = blockIdx.x * 256 + threadIdx.x;
    int v = (i < n) ? cnt[i] : 0;
    lds[threadIdx.x] = v;
    __syncthreads();
    for (int s = 128; s > 0; s >>= 1) {
        if (threadIdx.x < s) lds[threadIdx.x] += lds[threadIdx.x + s];
        __syncthreads();
    }
    if (threadIdx.x == 0) bsum[blockIdx.x] = lds[0];
}

// single block; nb <= 256
__global__ void scan_bsums(int* __restrict__ bsum, int nb) {
    __shared__ int lds[256];
    int t = threadIdx.x;
    int v = (t < nb) ? bsum[t] : 0;
    lds[t] = v;
    __syncthreads();
    for (int off = 1; off < 256; off <<= 1) {
        int u = (t >= off) ? lds[t - off] : 0;
        __syncthreads();
        lds[t] += u;
        __syncthreads();
    }
    if (t < nb) bsum[t] = lds[t] - v;  // exclusive
}

__global__ void scan_final(const int* __restrict__ cnt, const int* __restrict__ bsum,
                           int* __restrict__ start, int* __restrict__ cursor, int n) {
    __shared__ int lds[256];
    int t = threadIdx.x;
    int i = blockIdx.x * 256 + t;
    int v = (i < n) ? cnt[i] : 0;
    lds[t] = v;
    __syncthreads();
    for (int off = 1; off < 256; off <<= 1) {
        int u = (t >= off) ? lds[t - off] : 0;
        __syncthreads();
        lds[t] += u;
        __syncthreads();
    }
    if (i < n) {
        int excl = lds[t] - v + bsum[blockIdx.x];
        start[i]  = excl;
        cursor[i] = excl;
    }
}

__global__ void scatter_kernel(const int* __restrict__ row, const int* __restrict__ col,
                               int* __restrict__ cursor, int* __restrict__ srclist, int E) {
    int e = blockIdx.x * blockDim.x + threadIdx.x;
    if (e < E) {
        int p = atomicAdd(&cursor[col[e]], 1);
        srclist[p] = row[e];
    }
}

// ---------------------------------------------------------------------------
// GEMM: Y[n x OUT] = X[n x 128] @ W[128 x OUT] + bias.  fp32 vector ALU.
// ---------------------------------------------------------------------------
template <int OUT>
__global__ __launch_bounds__(256) void gemm_kernel(
    const float* __restrict__ X, const float* __restrict__ W,
    const float* __restrict__ bias, float* __restrict__ Y, int n) {
    constexpr int NCG  = OUT / 64;   // float4 col-groups per thread (1 or 2)
    constexpr int WPAD = OUT + 8;
    __shared__ float xs[64][36];
    __shared__ float wsh[32][WPAD];

    const int t  = threadIdx.x;
    const int tr = t >> 4;   // 0..15
    const int tc = t & 15;   // 0..15
    const int r0 = blockIdx.x * 64;

    float acc[4][NCG * 4];
#pragma unroll
    for (int i = 0; i < 4; ++i)
#pragma unroll
        for (int j = 0; j < NCG * 4; ++j) acc[i][j] = 0.f;

    for (int kc = 0; kc < 4; ++kc) {
#pragma unroll
        for (int q = 0; q < 2; ++q) {
            int f  = t + q * 256;
            int r  = f >> 3;
            int k4 = f & 7;
            int gr = r0 + r;
            if (gr >= n) gr = n - 1;
            float4 v = *(const float4*)&X[gr * 128 + kc * 32 + k4 * 4];
            *(float4*)&xs[r][k4 * 4] = v;
        }
#pragma unroll
        for (int q = 0; q < NCG * 2; ++q) {
            int f  = t + q * 256;
            int kk = f / (OUT / 4);
            int c4 = f % (OUT / 4);
            float4 v = *(const float4*)&W[(kc * 32 + kk) * OUT + c4 * 4];
            *(float4*)&wsh[kk][c4 * 4] = v;
        }
        __syncthreads();

#pragma unroll
        for (int k4 = 0; k4 < 8; ++k4) {
            float4 xv[4];
#pragma unroll
            for (int i = 0; i < 4; ++i)
                xv[i] = *(const float4*)&xs[tr * 4 + i][k4 * 4];
#pragma unroll
            for (int kk = 0; kk < 4; ++kk) {
#pragma unroll
                for (int g = 0; g < NCG; ++g) {
                    float4 wv = *(const float4*)&wsh[k4 * 4 + kk][g * 64 + tc * 4];
#pragma unroll
                    for (int i = 0; i < 4; ++i) {
                        float xk = ((const float*)&xv[i])[kk];
                        acc[i][g * 4 + 0] += xk * wv.x;
                        acc[i][g * 4 + 1] += xk * wv.y;
                        acc[i][g * 4 + 2] += xk * wv.z;
                        acc[i][g * 4 + 3] += xk * wv.w;
                    }
                }
            }
        }
        __syncthreads();
    }

#pragma unroll
    for (int g = 0; g < NCG; ++g) {
        float4 bv = *(const float4*)&bias[g * 64 + tc * 4];
#pragma unroll
        for (int i = 0; i < 4; ++i) {
            int r = r0 + tr * 4 + i;
            if (r < n) {
                float4 o;
                o.x = acc[i][g * 4 + 0] + bv.x;
                o.y = acc[i][g * 4 + 1] + bv.y;
                o.z = acc[i][g * 4 + 2] + bv.z;
                o.w = acc[i][g * 4 + 3] + bv.w;
                *(float4*)&Y[r * OUT + g * 64 + tc * 4] = o;
            }
        }
    }
}

// ---------------------------------------------------------------------------
// Aggregation: one wave per node. Lane-parallel index prefetch + __shfl
// broadcast; 8 independent gathers in flight per step.
// ---------------------------------------------------------------------------
template <bool RELU>
__global__ __launch_bounds__(256) void agg128_kernel(
    const float* __restrict__ h, const int* __restrict__ start,
    const int* __restrict__ cnt, const int* __restrict__ srclist,
    float* __restrict__ out, int n) {
    int wid  = (blockIdx.x * blockDim.x + threadIdx.x) >> 6;
    int lane = threadIdx.x & 63;
    if (wid >= n) return;
    int s0 = start[wid];
    int c  = cnt[wid];
    float ax = 0.f, ay = 0.f;
    for (int base = 0; base < c; base += 64) {
        int m = c - base;
        if (m > 64) m = 64;
        // one lane-parallel load covers up to 64 indices
        int idx = srclist[s0 + base + (lane < m ? lane : 0)];
        int e = 0;
        for (; e + 8 <= m; e += 8) {
            int i0 = __shfl(idx, e + 0), i1 = __shfl(idx, e + 1);
            int i2 = __shfl(idx, e + 2), i3 = __shfl(idx, e + 3);
            int i4 = __shfl(idx, e + 4), i5 = __shfl(idx, e + 5);
            int i6 = __shfl(idx, e + 6), i7 = __shfl(idx, e + 7);
            float2 v0 = *(const float2*)&h[(size_t)i0 * 128 + lane * 2];
            float2 v1 = *(const float2*)&h[(size_t)i1 * 128 + lane * 2];
            float2 v2 = *(const float2*)&h[(size_t)i2 * 128 + lane * 2];
            float2 v3 = *(const float2*)&h[(size_t)i3 * 128 + lane * 2];
            float2 v4 = *(const float2*)&h[(size_t)i4 * 128 + lane * 2];
            float2 v5 = *(const float2*)&h[(size_t)i5 * 128 + lane * 2];
            float2 v6 = *(const float2*)&h[(size_t)i6 * 128 + lane * 2];
            float2 v7 = *(const float2*)&h[(size_t)i7 * 128 + lane * 2];
            ax += ((v0.x + v1.x) + (v2.x + v3.x)) + ((v4.x + v5.x) + (v6.x + v7.x));
            ay += ((v0.y + v1.y) + (v2.y + v3.y)) + ((v4.y + v5.y) + (v6.y + v7.y));
        }
        for (; e + 4 <= m; e += 4) {
            int i0 = __shfl(idx, e + 0), i1 = __shfl(idx, e + 1);
            int i2 = __shfl(idx, e + 2), i3 = __shfl(idx, e + 3);
            float2 v0 = *(const float2*)&h[(size_t)i0 * 128 + lane * 2];
            float2 v1 = *(const float2*)&h[(size_t)i1 * 128 + lane * 2];
            float2 v2 = *(const float2*)&h[(size_t)i2 * 128 + lane * 2];
            float2 v3 = *(const float2*)&h[(size_t)i3 * 128 + lane * 2];
            ax += (v0.x + v1.x) + (v2.x + v3.x);
            ay += (v0.y + v1.y) + (v2.y + v3.y);
        }
        for (; e < m; ++e) {
            int i0 = __shfl(idx, e);
            float2 v0 = *(const float2*)&h[(size_t)i0 * 128 + lane * 2];
            ax += v0.x;
            ay += v0.y;
        }
    }
    float rx, ry;
    if (c > 0) {
        float inv = 1.f / (float)c;
        rx = ax * inv; ry = ay * inv;
    } else {
        float2 v = *(const float2*)&h[(size_t)wid * 128 + lane * 2];
        rx = v.x; ry = v.y;
    }
    if (RELU) { rx = fmaxf(rx, 0.f); ry = fmaxf(ry, 0.f); }
    float2 o; o.x = rx; o.y = ry;
    *(float2*)&out[(size_t)wid * 128 + lane * 2] = o;
}

// D=64 final layer: lane owns 1 float; fused log_softmax via wave shuffles.
__global__ __launch_bounds__(256) void agg64_logsoftmax_kernel(
    const float* __restrict__ h, const int* __restrict__ start,
    const int* __restrict__ cnt, const int* __restrict__ srclist,
    float* __restrict__ out, int n) {
    int wid  = (blockIdx.x * blockDim.x + threadIdx.x) >> 6;
    int lane = threadIdx.x & 63;
    if (wid >= n) return;
    int s0 = start[wid];
    int c  = cnt[wid];
    float a = 0.f;
    for (int base = 0; base < c; base += 64) {
        int m = c - base;
        if (m > 64) m = 64;
        int idx = srclist[s0 + base + (lane < m ? lane : 0)];
        int e = 0;
        for (; e + 8 <= m; e += 8) {
            int i0 = __shfl(idx, e + 0), i1 = __shfl(idx, e + 1);
            int i2 = __shfl(idx, e + 2), i3 = __shfl(idx, e + 3);
            int i4 = __shfl(idx, e + 4), i5 = __shfl(idx, e + 5);
            int i6 = __shfl(idx, e + 6), i7 = __shfl(idx, e + 7);
            float v0 = h[(size_t)i0 * 64 + lane], v1 = h[(size_t)i1 * 64 + lane];
            float v2 = h[(size_t)i2 * 64 + lane], v3 = h[(size_t)i3 * 64 + lane];
            float v4 = h[(size_t)i4 * 64 + lane], v5 = h[(size_t)i5 * 64 + lane];
            float v6 = h[(size_t)i6 * 64 + lane], v7 = h[(size_t)i7 * 64 + lane];
            a += ((v0 + v1) + (v2 + v3)) + ((v4 + v5) + (v6 + v7));
        }
        for (; e + 4 <= m; e += 4) {
            int i0 = __shfl(idx, e + 0), i1 = __shfl(idx, e + 1);
            int i2 = __shfl(idx, e + 2), i3 = __shfl(idx, e + 3);
            a += (h[(size_t)i0 * 64 + lane] + h[(size_t)i1 * 64 + lane]) +
                 (h[(size_t)i2 * 64 + lane] + h[(size_t)i3 * 64 + lane]);
        }
        for (; e < m; ++e) {
            int i0 = __shfl(idx, e);
            a += h[(size_t)i0 * 64 + lane];
        }
    }
    float v = (c > 0) ? a / (float)c : h[(size_t)wid * 64 + lane];

    float m = v;
#pragma unroll
    for (int off = 32; off > 0; off >>= 1) m = fmaxf(m, __shfl_xor(m, off));
    float ex = __expf(v - m);
    float s = ex;
#pragma unroll
    for (int off = 32; off > 0; off >>= 1) s += __shfl_xor(s, off);
    out[(size_t)wid * 64 + lane] = v - m - __logf(s);
}

// ---------------------------------------------------------------------------
extern "C" void kernel_launch(void* const* d_in, const int* in_sizes, int n_in,
                              void* d_out, int out_size, void* d_ws, size_t ws_size,
                              hipStream_t stream) {
    const float* x  = (const float*)d_in[0];
    const int*   ei = (const int*)d_in[1];
    const float* W1 = (const float*)d_in[2];
    const float* b1 = (const float*)d_in[3];
    const float* W2 = (const float*)d_in[4];
    const float* b2 = (const float*)d_in[5];
    const float* W3 = (const float*)d_in[6];
    const float* b3 = (const float*)d_in[7];
    float* out = (float*)d_out;

    const int n = in_sizes[0] / 128;
    const int E = in_sizes[1] / 2;
    const int* row = ei;        // edge_index[0]
    const int* col = ei + E;    // edge_index[1]

    char* ws = (char*)d_ws;
    size_t off = 0;
    auto carve = [&](size_t bytes) {
        char* p = ws + off;
        off = (off + bytes + 255) & ~(size_t)255;
        return p;
    };
    float* bufA    = (float*)carve((size_t)n * 128 * sizeof(float));
    float* bufB    = (float*)carve((size_t)n * 128 * sizeof(float));
    int*   cnt     = (int*)carve((size_t)n * sizeof(int));
    int*   start   = (int*)carve((size_t)n * sizeof(int));
    int*   cursor  = (int*)carve((size_t)n * sizeof(int));
    int*   srclist = (int*)carve((size_t)E * sizeof(int));
    int*   bsum    = (int*)carve(1024);

    // --- CSR build ---
    hipMemsetAsync(cnt, 0, (size_t)n * sizeof(int), stream);
    int egrid = (E + 255) / 256;
    int nb    = (n + 255) / 256;
    hist_kernel<<<egrid, 256, 0, stream>>>(col, cnt, E);
    scan_partial<<<nb, 256, 0, stream>>>(cnt, bsum, n);
    scan_bsums<<<1, 256, 0, stream>>>(bsum, nb);
    scan_final<<<nb, 256, 0, stream>>>(cnt, bsum, start, cursor, n);
    scatter_kernel<<<egrid, 256, 0, stream>>>(row, col, cursor, srclist, E);

    // --- 3 GCN layers ---
    int ggrid = (n + 63) / 64;
    int agrid = (n + 3) / 4;   // 4 waves/block, 1 node/wave
    gemm_kernel<128><<<ggrid, 256, 0, stream>>>(x, W1, b1, bufA, n);
    agg128_kernel<true><<<agrid, 256, 0, stream>>>(bufA, start, cnt, srclist, bufB, n);
    gemm_kernel<128><<<ggrid, 256, 0, stream>>>(bufB, W2, b2, bufA, n);
    agg128_kernel<true><<<agrid, 256, 0, stream>>>(bufA, start, cnt, srclist, bufB, n);
    gemm_kernel<64><<<ggrid, 256, 0, stream>>>(bufB, W3, b3, bufA, n);
    agg64_logsoftmax_kernel<<<agrid, 256, 0, stream>>>(bufA, start, cnt, srclist, out, n);
}

// Round 3
// 245.166 us; speedup vs baseline: 1.3908x; 1.2584x over previous
//
#include <hip/hip_runtime.h>
#include <hip/hip_bf16.h>

// ---------------------------------------------------------------------------
// GCN: 3 x (linear -> segment-mean -> [relu]) -> log_softmax
// R3: all intermediates bf16 (halves gather bytes, table L2-fits better),
//     GEMMs via mfma_f32_16x16x32_bf16 (fp32 accum), W repacked to fragment
//     order once per call. Agg gathers 1 dword/lane (2 bf16).
// ---------------------------------------------------------------------------

typedef __attribute__((ext_vector_type(8))) short short8v;
typedef __attribute__((ext_vector_type(4))) float f32x4;

static __device__ __forceinline__ ushort f2bf(float f) {
    __hip_bfloat16 h = __float2bfloat16(f);   // RNE
    return *reinterpret_cast<ushort*>(&h);
}
static __device__ __forceinline__ float bf_lo(uint u) { return __uint_as_float(u << 16); }
static __device__ __forceinline__ float bf_hi(uint u) { return __uint_as_float(u & 0xffff0000u); }

// ------------------------------- CSR build --------------------------------
__global__ void hist_kernel(const int* __restrict__ col, int* __restrict__ cnt, int E) {
    int e = blockIdx.x * blockDim.x + threadIdx.x;
    if (e < E) atomicAdd(&cnt[col[e]], 1);
}

__global__ void scan_partial(const int* __restrict__ cnt, int* __restrict__ bsum, int n) {
    __shared__ int lds[256];
    int i = blockIdx.x * 256 + threadIdx.x;
    int v = (i < n) ? cnt[i] : 0;
    lds[threadIdx.x] = v;
    __syncthreads();
    for (int s = 128; s > 0; s >>= 1) {
        if (threadIdx.x < s) lds[threadIdx.x] += lds[threadIdx.x + s];
        __syncthreads();
    }
    if (threadIdx.x == 0) bsum[blockIdx.x] = lds[0];
}

__global__ void scan_bsums(int* __restrict__ bsum, int nb) {
    __shared__ int lds[256];
    int t = threadIdx.x;
    int v = (t < nb) ? bsum[t] : 0;
    lds[t] = v;
    __syncthreads();
    for (int off = 1; off < 256; off <<= 1) {
        int u = (t >= off) ? lds[t - off] : 0;
        __syncthreads();
        lds[t] += u;
        __syncthreads();
    }
    if (t < nb) bsum[t] = lds[t] - v;  // exclusive
}

__global__ void scan_final(const int* __restrict__ cnt, const int* __restrict__ bsum,
                           int* __restrict__ start, int* __restrict__ cursor, int n) {
    __shared__ int lds[256];
    int t = threadIdx.x;
    int i = blockIdx.x * 256 + t;
    int v = (i < n) ? cnt[i] : 0;
    lds[t] = v;
    __syncthreads();
    for (int off = 1; off < 256; off <<= 1) {
        int u = (t >= off) ? lds[t - off] : 0;
        __syncthreads();
        lds[t] += u;
        __syncthreads();
    }
    if (i < n) {
        int excl = lds[t] - v + bsum[blockIdx.x];
        start[i]  = excl;
        cursor[i] = excl;
    }
}

__global__ void scatter_kernel(const int* __restrict__ row, const int* __restrict__ col,
                               int* __restrict__ cursor, int* __restrict__ srclist, int E) {
    int e = blockIdx.x * blockDim.x + threadIdx.x;
    if (e < E) {
        int p = atomicAdd(&cursor[col[e]], 1);
        srclist[p] = row[e];
    }
}

// --------------------------- prep: cast & repack ---------------------------
// x fp32 -> bf16, 8 elems/thread
__global__ void cast_f32_bf16(const float* __restrict__ in, ushort* __restrict__ outp,
                              int total8) {
    int i = blockIdx.x * blockDim.x + threadIdx.x;
    if (i >= total8) return;
    float4 a = ((const float4*)in)[2 * i];
    float4 b = ((const float4*)in)[2 * i + 1];
    uint4 o;
    o.x = ((uint)f2bf(a.y) << 16) | f2bf(a.x);
    o.y = ((uint)f2bf(a.w) << 16) | f2bf(a.z);
    o.z = ((uint)f2bf(b.y) << 16) | f2bf(b.x);
    o.w = ((uint)f2bf(b.w) << 16) | f2bf(b.z);
    ((uint4*)outp)[i] = o;
}

// W[K=128][OUT] fp32 -> fragment-ordered bf16: Wf[kt][ct][lane][j]
// lane: c = lane&15, kb = lane>>4 ; element = W[(kt*32 + kb*8 + j)*OUT + ct*16 + c]
__global__ void repack_w(const float* __restrict__ W, ushort* __restrict__ Wf,
                         int OUT) {
    int CT = OUT / 16;
    int tid = blockIdx.x * blockDim.x + threadIdx.x;
    int total = 4 * CT * 64;
    if (tid >= total) return;
    int kt   = tid / (CT * 64);
    int rem  = tid % (CT * 64);
    int ct   = rem / 64;
    int lane = rem % 64;
    int c  = lane & 15;
    int kb = lane >> 4;
    ushort tmp[8];
#pragma unroll
    for (int j = 0; j < 8; ++j)
        tmp[j] = f2bf(W[(kt * 32 + kb * 8 + j) * OUT + ct * 16 + c]);
    uint4 o;
    o.x = ((uint)tmp[1] << 16) | tmp[0];
    o.y = ((uint)tmp[3] << 16) | tmp[2];
    o.z = ((uint)tmp[5] << 16) | tmp[4];
    o.w = ((uint)tmp[7] << 16) | tmp[6];
    ((uint4*)Wf)[tid] = o;
}

// ------------------------------- MFMA GEMM --------------------------------
// Y[n x OUT] = X[n x 128] @ W + bias ; X,Y bf16, W fragment-ordered bf16.
// 1 wave per 16-row tile; 4 k-tiles; CT col-tiles; no LDS.
template <int OUT>
__global__ __launch_bounds__(256) void gemm_mfma(
    const ushort* __restrict__ X, const ushort* __restrict__ Wf,
    const float* __restrict__ bias, ushort* __restrict__ Y, int n) {
    constexpr int CT = OUT / 16;
    int wid  = (blockIdx.x * 256 + threadIdx.x) >> 6;
    int lane = threadIdx.x & 63;
    int r0   = wid * 16;
    if (r0 >= n) return;
    int arow = r0 + (lane & 15);
    if (arow >= n) arow = n - 1;
    int kb = lane >> 4;

    f32x4 acc[CT];
#pragma unroll
    for (int ct = 0; ct < CT; ++ct) acc[ct] = (f32x4)(0.f);

#pragma unroll
    for (int kt = 0; kt < 4; ++kt) {
        short8v a = *(const short8v*)&X[(size_t)arow * 128 + kt * 32 + kb * 8];
#pragma unroll
        for (int ct = 0; ct < CT; ++ct) {
            short8v b = *(const short8v*)&Wf[(size_t)((kt * CT + ct) * 64 + lane) * 8];
            acc[ct] = __builtin_amdgcn_mfma_f32_16x16x32_bf16(a, b, acc[ct], 0, 0, 0);
        }
    }

    int c  = lane & 15;
    int rg = lane >> 4;
#pragma unroll
    for (int ct = 0; ct < CT; ++ct) {
        float bv = bias[ct * 16 + c];
#pragma unroll
        for (int j = 0; j < 4; ++j) {
            int r = r0 + rg * 4 + j;
            if (r < n) Y[(size_t)r * OUT + ct * 16 + c] = f2bf(acc[ct][j] + bv);
        }
    }
}

// ------------------------------ aggregation -------------------------------
// One wave per node; lane owns 2 bf16 (1 dword). Lane-parallel index
// prefetch + __shfl broadcast; 8 independent gathers in flight.
template <bool RELU>
__global__ __launch_bounds__(256) void agg128_bf16(
    const ushort* __restrict__ h, const int* __restrict__ start,
    const int* __restrict__ cnt, const int* __restrict__ srclist,
    ushort* __restrict__ out, int n) {
    int wid  = (blockIdx.x * blockDim.x + threadIdx.x) >> 6;
    int lane = threadIdx.x & 63;
    if (wid >= n) return;
    const uint* h32 = (const uint*)h;   // [n][64] dwords
    int s0 = start[wid];
    int c  = cnt[wid];
    float ax = 0.f, ay = 0.f;
    for (int base = 0; base < c; base += 64) {
        int m = c - base;
        if (m > 64) m = 64;
        int idx = srclist[s0 + base + (lane < m ? lane : 0)];
        int e = 0;
        for (; e + 8 <= m; e += 8) {
            int i0 = __shfl(idx, e + 0), i1 = __shfl(idx, e + 1);
            int i2 = __shfl(idx, e + 2), i3 = __shfl(idx, e + 3);
            int i4 = __shfl(idx, e + 4), i5 = __shfl(idx, e + 5);
            int i6 = __shfl(idx, e + 6), i7 = __shfl(idx, e + 7);
            uint u0 = h32[(size_t)i0 * 64 + lane];
            uint u1 = h32[(size_t)i1 * 64 + lane];
            uint u2 = h32[(size_t)i2 * 64 + lane];
            uint u3 = h32[(size_t)i3 * 64 + lane];
            uint u4 = h32[(size_t)i4 * 64 + lane];
            uint u5 = h32[(size_t)i5 * 64 + lane];
            uint u6 = h32[(size_t)i6 * 64 + lane];
            uint u7 = h32[(size_t)i7 * 64 + lane];
            ax += ((bf_lo(u0) + bf_lo(u1)) + (bf_lo(u2) + bf_lo(u3))) +
                  ((bf_lo(u4) + bf_lo(u5)) + (bf_lo(u6) + bf_lo(u7)));
            ay += ((bf_hi(u0) + bf_hi(u1)) + (bf_hi(u2) + bf_hi(u3))) +
                  ((bf_hi(u4) + bf_hi(u5)) + (bf_hi(u6) + bf_hi(u7)));
        }
        for (; e + 4 <= m; e += 4) {
            int i0 = __shfl(idx, e + 0), i1 = __shfl(idx, e + 1);
            int i2 = __shfl(idx, e + 2), i3 = __shfl(idx, e + 3);
            uint u0 = h32[(size_t)i0 * 64 + lane];
            uint u1 = h32[(size_t)i1 * 64 + lane];
            uint u2 = h32[(size_t)i2 * 64 + lane];
            uint u3 = h32[(size_t)i3 * 64 + lane];
            ax += (bf_lo(u0) + bf_lo(u1)) + (bf_lo(u2) + bf_lo(u3));
            ay += (bf_hi(u0) + bf_hi(u1)) + (bf_hi(u2) + bf_hi(u3));
        }
        for (; e < m; ++e) {
            int i0 = __shfl(idx, e);
            uint u0 = h32[(size_t)i0 * 64 + lane];
            ax += bf_lo(u0);
            ay += bf_hi(u0);
        }
    }
    float rx, ry;
    if (c > 0) {
        float inv = 1.f / (float)c;
        rx = ax * inv; ry = ay * inv;
    } else {
        uint u = h32[(size_t)wid * 64 + lane];
        rx = bf_lo(u); ry = bf_hi(u);
    }
    if (RELU) { rx = fmaxf(rx, 0.f); ry = fmaxf(ry, 0.f); }
    ((uint*)out)[(size_t)wid * 64 + lane] = ((uint)f2bf(ry) << 16) | f2bf(rx);
}

// D=64 final layer: lane owns 1 bf16; fused log_softmax; fp32 output.
__global__ __launch_bounds__(256) void agg64_lsm_bf16(
    const ushort* __restrict__ h, const int* __restrict__ start,
    const int* __restrict__ cnt, const int* __restrict__ srclist,
    float* __restrict__ out, int n) {
    int wid  = (blockIdx.x * blockDim.x + threadIdx.x) >> 6;
    int lane = threadIdx.x & 63;
    if (wid >= n) return;
    int s0 = start[wid];
    int c  = cnt[wid];
    float a = 0.f;
    for (int base = 0; base < c; base += 64) {
        int m = c - base;
        if (m > 64) m = 64;
        int idx = srclist[s0 + base + (lane < m ? lane : 0)];
        int e = 0;
        for (; e + 8 <= m; e += 8) {
            int i0 = __shfl(idx, e + 0), i1 = __shfl(idx, e + 1);
            int i2 = __shfl(idx, e + 2), i3 = __shfl(idx, e + 3);
            int i4 = __shfl(idx, e + 4), i5 = __shfl(idx, e + 5);
            int i6 = __shfl(idx, e + 6), i7 = __shfl(idx, e + 7);
            float v0 = __uint_as_float((uint)h[(size_t)i0 * 64 + lane] << 16);
            float v1 = __uint_as_float((uint)h[(size_t)i1 * 64 + lane] << 16);
            float v2 = __uint_as_float((uint)h[(size_t)i2 * 64 + lane] << 16);
            float v3 = __uint_as_float((uint)h[(size_t)i3 * 64 + lane] << 16);
            float v4 = __uint_as_float((uint)h[(size_t)i4 * 64 + lane] << 16);
            float v5 = __uint_as_float((uint)h[(size_t)i5 * 64 + lane] << 16);
            float v6 = __uint_as_float((uint)h[(size_t)i6 * 64 + lane] << 16);
            float v7 = __uint_as_float((uint)h[(size_t)i7 * 64 + lane] << 16);
            a += ((v0 + v1) + (v2 + v3)) + ((v4 + v5) + (v6 + v7));
        }
        for (; e < m; ++e) {
            int i0 = __shfl(idx, e);
            a += __uint_as_float((uint)h[(size_t)i0 * 64 + lane] << 16);
        }
    }
    float v = (c > 0) ? a / (float)c
                      : __uint_as_float((uint)h[(size_t)wid * 64 + lane] << 16);

    float m = v;
#pragma unroll
    for (int off = 32; off > 0; off >>= 1) m = fmaxf(m, __shfl_xor(m, off));
    float ex = __expf(v - m);
    float s = ex;
#pragma unroll
    for (int off = 32; off > 0; off >>= 1) s += __shfl_xor(s, off);
    out[(size_t)wid * 64 + lane] = v - m - __logf(s);
}

// ---------------------------------------------------------------------------
extern "C" void kernel_launch(void* const* d_in, const int* in_sizes, int n_in,
                              void* d_out, int out_size, void* d_ws, size_t ws_size,
                              hipStream_t stream) {
    const float* x  = (const float*)d_in[0];
    const int*   ei = (const int*)d_in[1];
    const float* W1 = (const float*)d_in[2];
    const float* b1 = (const float*)d_in[3];
    const float* W2 = (const float*)d_in[4];
    const float* b2 = (const float*)d_in[5];
    const float* W3 = (const float*)d_in[6];
    const float* b3 = (const float*)d_in[7];
    float* out = (float*)d_out;

    const int n = in_sizes[0] / 128;
    const int E = in_sizes[1] / 2;
    const int* row = ei;        // edge_index[0]
    const int* col = ei + E;    // edge_index[1]

    char* ws = (char*)d_ws;
    size_t off = 0;
    auto carve = [&](size_t bytes) {
        char* p = ws + off;
        off = (off + bytes + 255) & ~(size_t)255;
        return p;
    };
    ushort* xbf     = (ushort*)carve((size_t)n * 128 * 2);
    ushort* hbuf    = (ushort*)carve((size_t)n * 128 * 2);   // gemm out / agg in
    ushort* abuf    = (ushort*)carve((size_t)n * 128 * 2);   // agg out / gemm in
    ushort* Wf1     = (ushort*)carve(4 * 8 * 64 * 8 * 2);
    ushort* Wf2     = (ushort*)carve(4 * 8 * 64 * 8 * 2);
    ushort* Wf3     = (ushort*)carve(4 * 4 * 64 * 8 * 2);
    int*    cnt     = (int*)carve((size_t)n * sizeof(int));
    int*    start   = (int*)carve((size_t)n * sizeof(int));
    int*    cursor  = (int*)carve((size_t)n * sizeof(int));
    int*    srclist = (int*)carve((size_t)E * sizeof(int));
    int*    bsum    = (int*)carve(1024);

    // --- CSR build ---
    hipMemsetAsync(cnt, 0, (size_t)n * sizeof(int), stream);
    int egrid = (E + 255) / 256;
    int nb    = (n + 255) / 256;
    hist_kernel<<<egrid, 256, 0, stream>>>(col, cnt, E);
    scan_partial<<<nb, 256, 0, stream>>>(cnt, bsum, n);
    scan_bsums<<<1, 256, 0, stream>>>(bsum, nb);
    scan_final<<<nb, 256, 0, stream>>>(cnt, bsum, start, cursor, n);
    scatter_kernel<<<egrid, 256, 0, stream>>>(row, col, cursor, srclist, E);

    // --- prep: cast x, repack weights ---
    int total8 = n * 16;   // n*128/8
    cast_f32_bf16<<<(total8 + 255) / 256, 256, 0, stream>>>(x, xbf, total8);
    repack_w<<<(4 * 8 * 64 + 255) / 256, 256, 0, stream>>>(W1, Wf1, 128);
    repack_w<<<(4 * 8 * 64 + 255) / 256, 256, 0, stream>>>(W2, Wf2, 128);
    repack_w<<<(4 * 4 * 64 + 255) / 256, 256, 0, stream>>>(W3, Wf3, 64);

    // --- 3 GCN layers ---
    int nwave = (n + 15) / 16;                 // 16-row tiles
    int ggrid = (nwave + 3) / 4;               // 4 waves/block
    int agrid = (n + 3) / 4;                   // 1 node/wave
    gemm_mfma<128><<<ggrid, 256, 0, stream>>>(xbf, Wf1, b1, hbuf, n);
    agg128_bf16<true><<<agrid, 256, 0, stream>>>(hbuf, start, cnt, srclist, abuf, n);
    gemm_mfma<128><<<ggrid, 256, 0, stream>>>(abuf, Wf2, b2, hbuf, n);
    agg128_bf16<true><<<agrid, 256, 0, stream>>>(hbuf, start, cnt, srclist, abuf, n);
    gemm_mfma<64><<<ggrid, 256, 0, stream>>>(abuf, Wf3, b3, hbuf, n);
    agg64_lsm_bf16<<<agrid, 256, 0, stream>>>(hbuf, start, cnt, srclist, out, n);
}

// Round 4
// 192.816 us; speedup vs baseline: 1.7684x; 1.2715x over previous
//
#include <hip/hip_runtime.h>
#include <hip/hip_bf16.h>

// ---------------------------------------------------------------------------
// GCN: 3 x (linear -> segment-mean -> [relu]) -> log_softmax
// R4: CSR build was the top cost (scatter 50us, 52MB write-allocate from
//     random 4B stores + 2x800k atomics). Changes:
//     - rank trick: single atomic pass (hist returns within-bucket rank),
//       scatter pass is atomic-free with coalesced reads
//     - ushort srclist/rank (N < 65536) halves scattered write bytes
//     - fuse independent dispatches: [hist | cast | repack] and [scatter | gemm1]
// NOTE: assumes n < 65536 (problem fixes N=50000).
// ---------------------------------------------------------------------------

typedef __attribute__((ext_vector_type(8))) short short8v;
typedef __attribute__((ext_vector_type(4))) float f32x4;

static __device__ __forceinline__ ushort f2bf(float f) {
    __hip_bfloat16 h = __float2bfloat16(f);   // RNE
    return *reinterpret_cast<ushort*>(&h);
}
static __device__ __forceinline__ float bf_lo(uint u) { return __uint_as_float(u << 16); }
static __device__ __forceinline__ float bf_hi(uint u) { return __uint_as_float(u & 0xffff0000u); }

// ---------------- fused prep: hist+rank | x cast | W repacks ---------------
__global__ __launch_bounds__(256) void fused_prep(
    const int* __restrict__ col, int* __restrict__ cnt, ushort* __restrict__ rank16,
    const float* __restrict__ x, ushort* __restrict__ xbf,
    const float* __restrict__ W1, ushort* __restrict__ Wf1,
    const float* __restrict__ W2, ushort* __restrict__ Wf2,
    const float* __restrict__ W3, ushort* __restrict__ Wf3,
    int n, int E) {
    int b = blockIdx.x, t = threadIdx.x;
    const int HB = (E + 255) >> 8;
    const int CB = (n * 16 + 255) >> 8;
    if (b < HB) {
        int e = b * 256 + t;
        if (e < E) rank16[e] = (ushort)atomicAdd(&cnt[col[e]], 1);
        return;
    }
    b -= HB;
    if (b < CB) {
        int i = b * 256 + t;
        if (i < n * 16) {
            float4 a = ((const float4*)x)[2 * i];
            float4 c = ((const float4*)x)[2 * i + 1];
            uint4 o;
            o.x = ((uint)f2bf(a.y) << 16) | f2bf(a.x);
            o.y = ((uint)f2bf(a.w) << 16) | f2bf(a.z);
            o.z = ((uint)f2bf(c.y) << 16) | f2bf(c.x);
            o.w = ((uint)f2bf(c.w) << 16) | f2bf(c.z);
            ((uint4*)xbf)[i] = o;
        }
        return;
    }
    b -= CB;
    // repack blocks: W1 [0,8), W2 [8,16), W3 [16,20)
    const float* W; ushort* Wf; int OUT; int tid;
    if (b < 8)       { W = W1; Wf = Wf1; OUT = 128; tid = b * 256 + t; }
    else if (b < 16) { W = W2; Wf = Wf2; OUT = 128; tid = (b - 8) * 256 + t; }
    else             { W = W3; Wf = Wf3; OUT = 64;  tid = (b - 16) * 256 + t; }
    int CT = OUT >> 4;
    int total = 4 * CT * 64;
    if (tid >= total) return;
    int kt   = tid / (CT * 64);
    int rem  = tid % (CT * 64);
    int ct   = rem >> 6;
    int lane = rem & 63;
    int c  = lane & 15;
    int kb = lane >> 4;
    ushort tmp[8];
#pragma unroll
    for (int j = 0; j < 8; ++j)
        tmp[j] = f2bf(W[(kt * 32 + kb * 8 + j) * OUT + ct * 16 + c]);
    uint4 o;
    o.x = ((uint)tmp[1] << 16) | tmp[0];
    o.y = ((uint)tmp[3] << 16) | tmp[2];
    o.z = ((uint)tmp[5] << 16) | tmp[4];
    o.w = ((uint)tmp[7] << 16) | tmp[6];
    ((uint4*)Wf)[tid] = o;
}

// ------------------------------- scan (cnt -> start) -----------------------
__global__ void scan_partial(const int* __restrict__ cnt, int* __restrict__ bsum, int n) {
    __shared__ int lds[256];
    int i = blockIdx.x * 256 + threadIdx.x;
    int v = (i < n) ? cnt[i] : 0;
    lds[threadIdx.x] = v;
    __syncthreads();
    for (int s = 128; s > 0; s >>= 1) {
        if (threadIdx.x < s) lds[threadIdx.x] += lds[threadIdx.x + s];
        __syncthreads();
    }
    if (threadIdx.x == 0) bsum[blockIdx.x] = lds[0];
}

__global__ void scan_bsums(int* __restrict__ bsum, int nb) {
    __shared__ int lds[256];
    int t = threadIdx.x;
    int v = (t < nb) ? bsum[t] : 0;
    lds[t] = v;
    __syncthreads();
    for (int off = 1; off < 256; off <<= 1) {
        int u = (t >= off) ? lds[t - off] : 0;
        __syncthreads();
        lds[t] += u;
        __syncthreads();
    }
    if (t < nb) bsum[t] = lds[t] - v;  // exclusive
}

__global__ void scan_final(const int* __restrict__ cnt, const int* __restrict__ bsum,
                           int* __restrict__ start, int n) {
    __shared__ int lds[256];
    int t = threadIdx.x;
    int i = blockIdx.x * 256 + t;
    int v = (i < n) ? cnt[i] : 0;
    lds[t] = v;
    __syncthreads();
    for (int off = 1; off < 256; off <<= 1) {
        int u = (t >= off) ? lds[t - off] : 0;
        __syncthreads();
        lds[t] += u;
        __syncthreads();
    }
    if (i < n) start[i] = lds[t] - v + bsum[blockIdx.x];
}

// ------------------------------- MFMA GEMM body ----------------------------
template <int OUT>
static __device__ __forceinline__ void gemm_body(
    const ushort* __restrict__ X, const ushort* __restrict__ Wf,
    const float* __restrict__ bias, ushort* __restrict__ Y, int n,
    int wid, int lane) {
    constexpr int CT = OUT / 16;
    int r0 = wid * 16;
    if (r0 >= n) return;
    int arow = r0 + (lane & 15);
    if (arow >= n) arow = n - 1;
    int kb = lane >> 4;

    f32x4 acc[CT];
#pragma unroll
    for (int ct = 0; ct < CT; ++ct) acc[ct] = (f32x4)(0.f);

#pragma unroll
    for (int kt = 0; kt < 4; ++kt) {
        short8v a = *(const short8v*)&X[(size_t)arow * 128 + kt * 32 + kb * 8];
#pragma unroll
        for (int ct = 0; ct < CT; ++ct) {
            short8v b = *(const short8v*)&Wf[(size_t)((kt * CT + ct) * 64 + lane) * 8];
            acc[ct] = __builtin_amdgcn_mfma_f32_16x16x32_bf16(a, b, acc[ct], 0, 0, 0);
        }
    }

    int c  = lane & 15;
    int rg = lane >> 4;
#pragma unroll
    for (int ct = 0; ct < CT; ++ct) {
        float bv = bias[ct * 16 + c];
#pragma unroll
        for (int j = 0; j < 4; ++j) {
            int r = r0 + rg * 4 + j;
            if (r < n) Y[(size_t)r * OUT + ct * 16 + c] = f2bf(acc[ct][j] + bv);
        }
    }
}

template <int OUT>
__global__ __launch_bounds__(256) void gemm_mfma(
    const ushort* __restrict__ X, const ushort* __restrict__ Wf,
    const float* __restrict__ bias, ushort* __restrict__ Y, int n) {
    int wid  = (blockIdx.x * 256 + threadIdx.x) >> 6;
    gemm_body<OUT>(X, Wf, bias, Y, n, wid, threadIdx.x & 63);
}

// --------------- fused: atomic-free scatter | gemm layer 1 -----------------
__global__ __launch_bounds__(256) void fused_scatter_gemm1(
    const int* __restrict__ row, const int* __restrict__ col,
    const int* __restrict__ start, const ushort* __restrict__ rank16,
    ushort* __restrict__ srclist16,
    const ushort* __restrict__ xbf, const ushort* __restrict__ Wf1,
    const float* __restrict__ b1, ushort* __restrict__ hbuf,
    int n, int E) {
    int b = blockIdx.x, t = threadIdx.x;
    const int SB = (E + 255) >> 8;
    if (b < SB) {
        int e = b * 256 + t;
        if (e < E) {
            int d = col[e];
            srclist16[start[d] + (int)rank16[e]] = (ushort)row[e];
        }
        return;
    }
    int wid = ((b - SB) * 256 + t) >> 6;
    gemm_body<128>(xbf, Wf1, b1, hbuf, n, wid, t & 63);
}

// ------------------------------ aggregation --------------------------------
template <bool RELU>
__global__ __launch_bounds__(256) void agg128_bf16(
    const ushort* __restrict__ h, const int* __restrict__ start,
    const int* __restrict__ cnt, const ushort* __restrict__ srclist16,
    ushort* __restrict__ out, int n) {
    int wid  = (blockIdx.x * blockDim.x + threadIdx.x) >> 6;
    int lane = threadIdx.x & 63;
    if (wid >= n) return;
    const uint* h32 = (const uint*)h;   // [n][64] dwords
    int s0 = start[wid];
    int c  = cnt[wid];
    float ax = 0.f, ay = 0.f;
    for (int base = 0; base < c; base += 64) {
        int m = c - base;
        if (m > 64) m = 64;
        int idx = (int)srclist16[s0 + base + (lane < m ? lane : 0)];
        int e = 0;
        for (; e + 8 <= m; e += 8) {
            int i0 = __shfl(idx, e + 0), i1 = __shfl(idx, e + 1);
            int i2 = __shfl(idx, e + 2), i3 = __shfl(idx, e + 3);
            int i4 = __shfl(idx, e + 4), i5 = __shfl(idx, e + 5);
            int i6 = __shfl(idx, e + 6), i7 = __shfl(idx, e + 7);
            uint u0 = h32[(size_t)i0 * 64 + lane];
            uint u1 = h32[(size_t)i1 * 64 + lane];
            uint u2 = h32[(size_t)i2 * 64 + lane];
            uint u3 = h32[(size_t)i3 * 64 + lane];
            uint u4 = h32[(size_t)i4 * 64 + lane];
            uint u5 = h32[(size_t)i5 * 64 + lane];
            uint u6 = h32[(size_t)i6 * 64 + lane];
            uint u7 = h32[(size_t)i7 * 64 + lane];
            ax += ((bf_lo(u0) + bf_lo(u1)) + (bf_lo(u2) + bf_lo(u3))) +
                  ((bf_lo(u4) + bf_lo(u5)) + (bf_lo(u6) + bf_lo(u7)));
            ay += ((bf_hi(u0) + bf_hi(u1)) + (bf_hi(u2) + bf_hi(u3))) +
                  ((bf_hi(u4) + bf_hi(u5)) + (bf_hi(u6) + bf_hi(u7)));
        }
        for (; e + 4 <= m; e += 4) {
            int i0 = __shfl(idx, e + 0), i1 = __shfl(idx, e + 1);
            int i2 = __shfl(idx, e + 2), i3 = __shfl(idx, e + 3);
            uint u0 = h32[(size_t)i0 * 64 + lane];
            uint u1 = h32[(size_t)i1 * 64 + lane];
            uint u2 = h32[(size_t)i2 * 64 + lane];
            uint u3 = h32[(size_t)i3 * 64 + lane];
            ax += (bf_lo(u0) + bf_lo(u1)) + (bf_lo(u2) + bf_lo(u3));
            ay += (bf_hi(u0) + bf_hi(u1)) + (bf_hi(u2) + bf_hi(u3));
        }
        for (; e < m; ++e) {
            int i0 = __shfl(idx, e);
            uint u0 = h32[(size_t)i0 * 64 + lane];
            ax += bf_lo(u0);
            ay += bf_hi(u0);
        }
    }
    float rx, ry;
    if (c > 0) {
        float inv = 1.f / (float)c;
        rx = ax * inv; ry = ay * inv;
    } else {
        uint u = h32[(size_t)wid * 64 + lane];
        rx = bf_lo(u); ry = bf_hi(u);
    }
    if (RELU) { rx = fmaxf(rx, 0.f); ry = fmaxf(ry, 0.f); }
    ((uint*)out)[(size_t)wid * 64 + lane] = ((uint)f2bf(ry) << 16) | f2bf(rx);
}

// D=64 final layer: lane owns 1 bf16; fused log_softmax; fp32 output.
__global__ __launch_bounds__(256) void agg64_lsm_bf16(
    const ushort* __restrict__ h, const int* __restrict__ start,
    const int* __restrict__ cnt, const ushort* __restrict__ srclist16,
    float* __restrict__ out, int n) {
    int wid  = (blockIdx.x * blockDim.x + threadIdx.x) >> 6;
    int lane = threadIdx.x & 63;
    if (wid >= n) return;
    int s0 = start[wid];
    int c  = cnt[wid];
    float a = 0.f;
    for (int base = 0; base < c; base += 64) {
        int m = c - base;
        if (m > 64) m = 64;
        int idx = (int)srclist16[s0 + base + (lane < m ? lane : 0)];
        int e = 0;
        for (; e + 8 <= m; e += 8) {
            int i0 = __shfl(idx, e + 0), i1 = __shfl(idx, e + 1);
            int i2 = __shfl(idx, e + 2), i3 = __shfl(idx, e + 3);
            int i4 = __shfl(idx, e + 4), i5 = __shfl(idx, e + 5);
            int i6 = __shfl(idx, e + 6), i7 = __shfl(idx, e + 7);
            float v0 = __uint_as_float((uint)h[(size_t)i0 * 64 + lane] << 16);
            float v1 = __uint_as_float((uint)h[(size_t)i1 * 64 + lane] << 16);
            float v2 = __uint_as_float((uint)h[(size_t)i2 * 64 + lane] << 16);
            float v3 = __uint_as_float((uint)h[(size_t)i3 * 64 + lane] << 16);
            float v4 = __uint_as_float((uint)h[(size_t)i4 * 64 + lane] << 16);
            float v5 = __uint_as_float((uint)h[(size_t)i5 * 64 + lane] << 16);
            float v6 = __uint_as_float((uint)h[(size_t)i6 * 64 + lane] << 16);
            float v7 = __uint_as_float((uint)h[(size_t)i7 * 64 + lane] << 16);
            a += ((v0 + v1) + (v2 + v3)) + ((v4 + v5) + (v6 + v7));
        }
        for (; e < m; ++e) {
            int i0 = __shfl(idx, e);
            a += __uint_as_float((uint)h[(size_t)i0 * 64 + lane] << 16);
        }
    }
    float v = (c > 0) ? a / (float)c
                      : __uint_as_float((uint)h[(size_t)wid * 64 + lane] << 16);

    float m = v;
#pragma unroll
    for (int off = 32; off > 0; off >>= 1) m = fmaxf(m, __shfl_xor(m, off));
    float ex = __expf(v - m);
    float s = ex;
#pragma unroll
    for (int off = 32; off > 0; off >>= 1) s += __shfl_xor(s, off);
    out[(size_t)wid * 64 + lane] = v - m - __logf(s);
}

// ---------------------------------------------------------------------------
extern "C" void kernel_launch(void* const* d_in, const int* in_sizes, int n_in,
                              void* d_out, int out_size, void* d_ws, size_t ws_size,
                              hipStream_t stream) {
    const float* x  = (const float*)d_in[0];
    const int*   ei = (const int*)d_in[1];
    const float* W1 = (const float*)d_in[2];
    const float* b1 = (const float*)d_in[3];
    const float* W2 = (const float*)d_in[4];
    const float* b2 = (const float*)d_in[5];
    const float* W3 = (const float*)d_in[6];
    const float* b3 = (const float*)d_in[7];
    float* out = (float*)d_out;

    const int n = in_sizes[0] / 128;
    const int E = in_sizes[1] / 2;
    const int* row = ei;        // edge_index[0]
    const int* col = ei + E;    // edge_index[1]

    char* ws = (char*)d_ws;
    size_t off = 0;
    auto carve = [&](size_t bytes) {
        char* p = ws + off;
        off = (off + bytes + 255) & ~(size_t)255;
        return p;
    };
    ushort* xbf       = (ushort*)carve((size_t)n * 128 * 2);
    ushort* hbuf      = (ushort*)carve((size_t)n * 128 * 2);
    ushort* abuf      = (ushort*)carve((size_t)n * 128 * 2);
    ushort* Wf1       = (ushort*)carve(4 * 8 * 64 * 8 * 2);
    ushort* Wf2       = (ushort*)carve(4 * 8 * 64 * 8 * 2);
    ushort* Wf3       = (ushort*)carve(4 * 4 * 64 * 8 * 2);
    int*    cnt       = (int*)carve((size_t)n * sizeof(int));
    int*    start     = (int*)carve((size_t)n * sizeof(int));
    ushort* rank16    = (ushort*)carve((size_t)E * 2);
    ushort* srclist16 = (ushort*)carve((size_t)E * 2);
    int*    bsum      = (int*)carve(1024);

    const int HB = (E + 255) / 256;       // hist / scatter blocks
    const int CB = (n * 16 + 255) / 256;  // cast blocks
    const int nb = (n + 255) / 256;       // scan blocks (<=256)

    hipMemsetAsync(cnt, 0, (size_t)n * sizeof(int), stream);
    fused_prep<<<HB + CB + 20, 256, 0, stream>>>(col, cnt, rank16, x, xbf,
                                                 W1, Wf1, W2, Wf2, W3, Wf3, n, E);
    scan_partial<<<nb, 256, 0, stream>>>(cnt, bsum, n);
    scan_bsums<<<1, 256, 0, stream>>>(bsum, nb);
    scan_final<<<nb, 256, 0, stream>>>(cnt, bsum, start, n);

    const int nwave = (n + 15) / 16;
    const int GB    = (nwave + 3) / 4;    // gemm blocks (4 waves/block)
    const int agrid = (n + 3) / 4;        // 1 node/wave

    fused_scatter_gemm1<<<HB + GB, 256, 0, stream>>>(row, col, start, rank16,
                                                     srclist16, xbf, Wf1, b1,
                                                     hbuf, n, E);
    agg128_bf16<true><<<agrid, 256, 0, stream>>>(hbuf, start, cnt, srclist16, abuf, n);
    gemm_mfma<128><<<GB, 256, 0, stream>>>(abuf, Wf2, b2, hbuf, n);
    agg128_bf16<true><<<agrid, 256, 0, stream>>>(hbuf, start, cnt, srclist16, abuf, n);
    gemm_mfma<64><<<GB, 256, 0, stream>>>(abuf, Wf3, b3, hbuf, n);
    agg64_lsm_bf16<<<agrid, 256, 0, stream>>>(hbuf, start, cnt, srclist16, out, n);
}

// Round 5
// 186.029 us; speedup vs baseline: 1.8329x; 1.0365x over previous
//
#include <hip/hip_runtime.h>
#include <hip/hip_bf16.h>

// ---------------------------------------------------------------------------
// GCN: 3 x (linear -> segment-mean -> [relu]) -> log_softmax
// R5: - hipMemsetAsync(cnt) cost 42us (rocclr fill kernel) -> custom int4
//       zero kernel (~2us)
//     - GEMM1 fused INTO the hist kernel (reads fp32 x / fp32 W1 with inline
//       bf16 cvt; no xbf cast, no Wf1 repack) so MFMA work hides under the
//       800k-atomic histogram floor
//     - scatter standalone (atomic-free, ushort payloads)
// NOTE: assumes n < 65536 (problem fixes N=50000).
// ---------------------------------------------------------------------------

typedef __attribute__((ext_vector_type(8))) short short8v;
typedef __attribute__((ext_vector_type(4))) float f32x4;

static __device__ __forceinline__ ushort f2bf(float f) {
    __hip_bfloat16 h = __float2bfloat16(f);   // RNE
    return *reinterpret_cast<ushort*>(&h);
}
static __device__ __forceinline__ float bf_lo(uint u) { return __uint_as_float(u << 16); }
static __device__ __forceinline__ float bf_hi(uint u) { return __uint_as_float(u & 0xffff0000u); }

// ------------------------------ zero kernel --------------------------------
__global__ __launch_bounds__(256) void zero_cnt(int4* __restrict__ p, int n4) {
    int i = blockIdx.x * 256 + threadIdx.x;
    if (i < n4) p[i] = make_int4(0, 0, 0, 0);
}

// ------------------------- GEMM1 body (fp32 sources) -----------------------
// Y[n x 128] = bf16(X[n x 128]) @ bf16(W[128 x 128]) + bias, inline cvt.
static __device__ __forceinline__ void gemm1_body(
    const float* __restrict__ X, const float* __restrict__ W,
    const float* __restrict__ bias, ushort* __restrict__ Y, int n,
    int wid, int lane) {
    int r0 = wid * 16;
    if (r0 >= n) return;
    int arow = r0 + (lane & 15);
    if (arow >= n) arow = n - 1;
    int kb = lane >> 4;
    int c  = lane & 15;

    f32x4 acc[8];
#pragma unroll
    for (int ct = 0; ct < 8; ++ct) acc[ct] = (f32x4)(0.f);

#pragma unroll
    for (int kt = 0; kt < 4; ++kt) {
        const float* ap = &X[(size_t)arow * 128 + kt * 32 + kb * 8];
        float4 a0 = *(const float4*)ap;
        float4 a1 = *(const float4*)(ap + 4);
        union { short8v v; ushort u[8]; } av;
        av.u[0] = f2bf(a0.x); av.u[1] = f2bf(a0.y);
        av.u[2] = f2bf(a0.z); av.u[3] = f2bf(a0.w);
        av.u[4] = f2bf(a1.x); av.u[5] = f2bf(a1.y);
        av.u[6] = f2bf(a1.z); av.u[7] = f2bf(a1.w);
#pragma unroll
        for (int ct = 0; ct < 8; ++ct) {
            union { short8v v; ushort u[8]; } bv;
#pragma unroll
            for (int j = 0; j < 8; ++j)
                bv.u[j] = f2bf(W[(size_t)(kt * 32 + kb * 8 + j) * 128 + ct * 16 + c]);
            acc[ct] = __builtin_amdgcn_mfma_f32_16x16x32_bf16(av.v, bv.v, acc[ct], 0, 0, 0);
        }
    }

    int rg = lane >> 4;
#pragma unroll
    for (int ct = 0; ct < 8; ++ct) {
        float bvs = bias[ct * 16 + c];
#pragma unroll
        for (int j = 0; j < 4; ++j) {
            int r = r0 + rg * 4 + j;
            if (r < n) Y[(size_t)r * 128 + ct * 16 + c] = f2bf(acc[ct][j] + bvs);
        }
    }
}

// ---------------- fused: gemm1 | hist+rank | repack W2,W3 ------------------
__global__ __launch_bounds__(256) void fused_g1_hist(
    const float* __restrict__ x, const float* __restrict__ W1,
    const float* __restrict__ b1, ushort* __restrict__ hbuf,
    const int* __restrict__ col, int* __restrict__ cnt, ushort* __restrict__ rank16,
    const float* __restrict__ W2, ushort* __restrict__ Wf2,
    const float* __restrict__ W3, ushort* __restrict__ Wf3,
    int n, int E, int GB, int HB) {
    int b = blockIdx.x, t = threadIdx.x;
    if (b < GB) {
        int wid = (b * 256 + t) >> 6;
        gemm1_body(x, W1, b1, hbuf, n, wid, t & 63);
        return;
    }
    b -= GB;
    if (b < HB) {
        int e = b * 256 + t;
        if (e < E) rank16[e] = (ushort)atomicAdd(&cnt[col[e]], 1);
        return;
    }
    b -= HB;
    // repack: W2 blocks [0,8), W3 blocks [8,12)
    const float* W; ushort* Wf; int OUT; int tid;
    if (b < 8) { W = W2; Wf = Wf2; OUT = 128; tid = b * 256 + t; }
    else       { W = W3; Wf = Wf3; OUT = 64;  tid = (b - 8) * 256 + t; }
    int CT = OUT >> 4;
    int total = 4 * CT * 64;
    if (tid >= total) return;
    int kt   = tid / (CT * 64);
    int rem  = tid % (CT * 64);
    int ct   = rem >> 6;
    int lane = rem & 63;
    int c  = lane & 15;
    int kb = lane >> 4;
    ushort tmp[8];
#pragma unroll
    for (int j = 0; j < 8; ++j)
        tmp[j] = f2bf(W[(kt * 32 + kb * 8 + j) * OUT + ct * 16 + c]);
    uint4 o;
    o.x = ((uint)tmp[1] << 16) | tmp[0];
    o.y = ((uint)tmp[3] << 16) | tmp[2];
    o.z = ((uint)tmp[5] << 16) | tmp[4];
    o.w = ((uint)tmp[7] << 16) | tmp[6];
    ((uint4*)Wf)[tid] = o;
}

// ------------------------------- scan (cnt -> start) -----------------------
__global__ void scan_partial(const int* __restrict__ cnt, int* __restrict__ bsum, int n) {
    __shared__ int lds[256];
    int i = blockIdx.x * 256 + threadIdx.x;
    int v = (i < n) ? cnt[i] : 0;
    lds[threadIdx.x] = v;
    __syncthreads();
    for (int s = 128; s > 0; s >>= 1) {
        if (threadIdx.x < s) lds[threadIdx.x] += lds[threadIdx.x + s];
        __syncthreads();
    }
    if (threadIdx.x == 0) bsum[blockIdx.x] = lds[0];
}

__global__ void scan_bsums(int* __restrict__ bsum, int nb) {
    __shared__ int lds[256];
    int t = threadIdx.x;
    int v = (t < nb) ? bsum[t] : 0;
    lds[t] = v;
    __syncthreads();
    for (int off = 1; off < 256; off <<= 1) {
        int u = (t >= off) ? lds[t - off] : 0;
        __syncthreads();
        lds[t] += u;
        __syncthreads();
    }
    if (t < nb) bsum[t] = lds[t] - v;  // exclusive
}

__global__ void scan_final(const int* __restrict__ cnt, const int* __restrict__ bsum,
                           int* __restrict__ start, int n) {
    __shared__ int lds[256];
    int t = threadIdx.x;
    int i = blockIdx.x * 256 + t;
    int v = (i < n) ? cnt[i] : 0;
    lds[t] = v;
    __syncthreads();
    for (int off = 1; off < 256; off <<= 1) {
        int u = (t >= off) ? lds[t - off] : 0;
        __syncthreads();
        lds[t] += u;
        __syncthreads();
    }
    if (i < n) start[i] = lds[t] - v + bsum[blockIdx.x];
}

// ------------------------- atomic-free scatter -----------------------------
__global__ __launch_bounds__(256) void scatter16(
    const int* __restrict__ row, const int* __restrict__ col,
    const int* __restrict__ start, const ushort* __restrict__ rank16,
    ushort* __restrict__ srclist16, int E) {
    int e = blockIdx.x * 256 + threadIdx.x;
    if (e < E) {
        int d = col[e];
        srclist16[start[d] + (int)rank16[e]] = (ushort)row[e];
    }
}

// ------------------------------- MFMA GEMM (bf16 src) ----------------------
template <int OUT>
__global__ __launch_bounds__(256) void gemm_mfma(
    const ushort* __restrict__ X, const ushort* __restrict__ Wf,
    const float* __restrict__ bias, ushort* __restrict__ Y, int n) {
    constexpr int CT = OUT / 16;
    int wid  = (blockIdx.x * 256 + threadIdx.x) >> 6;
    int lane = threadIdx.x & 63;
    int r0 = wid * 16;
    if (r0 >= n) return;
    int arow = r0 + (lane & 15);
    if (arow >= n) arow = n - 1;
    int kb = lane >> 4;

    f32x4 acc[CT];
#pragma unroll
    for (int ct = 0; ct < CT; ++ct) acc[ct] = (f32x4)(0.f);

#pragma unroll
    for (int kt = 0; kt < 4; ++kt) {
        short8v a = *(const short8v*)&X[(size_t)arow * 128 + kt * 32 + kb * 8];
#pragma unroll
        for (int ct = 0; ct < CT; ++ct) {
            short8v b = *(const short8v*)&Wf[(size_t)((kt * CT + ct) * 64 + lane) * 8];
            acc[ct] = __builtin_amdgcn_mfma_f32_16x16x32_bf16(a, b, acc[ct], 0, 0, 0);
        }
    }

    int c  = lane & 15;
    int rg = lane >> 4;
#pragma unroll
    for (int ct = 0; ct < CT; ++ct) {
        float bv = bias[ct * 16 + c];
#pragma unroll
        for (int j = 0; j < 4; ++j) {
            int r = r0 + rg * 4 + j;
            if (r < n) Y[(size_t)r * OUT + ct * 16 + c] = f2bf(acc[ct][j] + bv);
        }
    }
}

// ------------------------------ aggregation --------------------------------
template <bool RELU>
__global__ __launch_bounds__(256) void agg128_bf16(
    const ushort* __restrict__ h, const int* __restrict__ start,
    const int* __restrict__ cnt, const ushort* __restrict__ srclist16,
    ushort* __restrict__ out, int n) {
    int wid  = (blockIdx.x * blockDim.x + threadIdx.x) >> 6;
    int lane = threadIdx.x & 63;
    if (wid >= n) return;
    const uint* h32 = (const uint*)h;   // [n][64] dwords
    int s0 = start[wid];
    int c  = cnt[wid];
    float ax = 0.f, ay = 0.f;
    for (int base = 0; base < c; base += 64) {
        int m = c - base;
        if (m > 64) m = 64;
        int idx = (int)srclist16[s0 + base + (lane < m ? lane : 0)];
        int e = 0;
        for (; e + 8 <= m; e += 8) {
            int i0 = __shfl(idx, e + 0), i1 = __shfl(idx, e + 1);
            int i2 = __shfl(idx, e + 2), i3 = __shfl(idx, e + 3);
            int i4 = __shfl(idx, e + 4), i5 = __shfl(idx, e + 5);
            int i6 = __shfl(idx, e + 6), i7 = __shfl(idx, e + 7);
            uint u0 = h32[(size_t)i0 * 64 + lane];
            uint u1 = h32[(size_t)i1 * 64 + lane];
            uint u2 = h32[(size_t)i2 * 64 + lane];
            uint u3 = h32[(size_t)i3 * 64 + lane];
            uint u4 = h32[(size_t)i4 * 64 + lane];
            uint u5 = h32[(size_t)i5 * 64 + lane];
            uint u6 = h32[(size_t)i6 * 64 + lane];
            uint u7 = h32[(size_t)i7 * 64 + lane];
            ax += ((bf_lo(u0) + bf_lo(u1)) + (bf_lo(u2) + bf_lo(u3))) +
                  ((bf_lo(u4) + bf_lo(u5)) + (bf_lo(u6) + bf_lo(u7)));
            ay += ((bf_hi(u0) + bf_hi(u1)) + (bf_hi(u2) + bf_hi(u3))) +
                  ((bf_hi(u4) + bf_hi(u5)) + (bf_hi(u6) + bf_hi(u7)));
        }
        for (; e + 4 <= m; e += 4) {
            int i0 = __shfl(idx, e + 0), i1 = __shfl(idx, e + 1);
            int i2 = __shfl(idx, e + 2), i3 = __shfl(idx, e + 3);
            uint u0 = h32[(size_t)i0 * 64 + lane];
            uint u1 = h32[(size_t)i1 * 64 + lane];
            uint u2 = h32[(size_t)i2 * 64 + lane];
            uint u3 = h32[(size_t)i3 * 64 + lane];
            ax += (bf_lo(u0) + bf_lo(u1)) + (bf_lo(u2) + bf_lo(u3));
            ay += (bf_hi(u0) + bf_hi(u1)) + (bf_hi(u2) + bf_hi(u3));
        }
        for (; e < m; ++e) {
            int i0 = __shfl(idx, e);
            uint u0 = h32[(size_t)i0 * 64 + lane];
            ax += bf_lo(u0);
            ay += bf_hi(u0);
        }
    }
    float rx, ry;
    if (c > 0) {
        float inv = 1.f / (float)c;
        rx = ax * inv; ry = ay * inv;
    } else {
        uint u = h32[(size_t)wid * 64 + lane];
        rx = bf_lo(u); ry = bf_hi(u);
    }
    if (RELU) { rx = fmaxf(rx, 0.f); ry = fmaxf(ry, 0.f); }
    ((uint*)out)[(size_t)wid * 64 + lane] = ((uint)f2bf(ry) << 16) | f2bf(rx);
}

// D=64 final layer: lane owns 1 bf16; fused log_softmax; fp32 output.
__global__ __launch_bounds__(256) void agg64_lsm_bf16(
    const ushort* __restrict__ h, const int* __restrict__ start,
    const int* __restrict__ cnt, const ushort* __restrict__ srclist16,
    float* __restrict__ out, int n) {
    int wid  = (blockIdx.x * blockDim.x + threadIdx.x) >> 6;
    int lane = threadIdx.x & 63;
    if (wid >= n) return;
    int s0 = start[wid];
    int c  = cnt[wid];
    float a = 0.f;
    for (int base = 0; base < c; base += 64) {
        int m = c - base;
        if (m > 64) m = 64;
        int idx = (int)srclist16[s0 + base + (lane < m ? lane : 0)];
        int e = 0;
        for (; e + 8 <= m; e += 8) {
            int i0 = __shfl(idx, e + 0), i1 = __shfl(idx, e + 1);
            int i2 = __shfl(idx, e + 2), i3 = __shfl(idx, e + 3);
            int i4 = __shfl(idx, e + 4), i5 = __shfl(idx, e + 5);
            int i6 = __shfl(idx, e + 6), i7 = __shfl(idx, e + 7);
            float v0 = __uint_as_float((uint)h[(size_t)i0 * 64 + lane] << 16);
            float v1 = __uint_as_float((uint)h[(size_t)i1 * 64 + lane] << 16);
            float v2 = __uint_as_float((uint)h[(size_t)i2 * 64 + lane] << 16);
            float v3 = __uint_as_float((uint)h[(size_t)i3 * 64 + lane] << 16);
            float v4 = __uint_as_float((uint)h[(size_t)i4 * 64 + lane] << 16);
            float v5 = __uint_as_float((uint)h[(size_t)i5 * 64 + lane] << 16);
            float v6 = __uint_as_float((uint)h[(size_t)i6 * 64 + lane] << 16);
            float v7 = __uint_as_float((uint)h[(size_t)i7 * 64 + lane] << 16);
            a += ((v0 + v1) + (v2 + v3)) + ((v4 + v5) + (v6 + v7));
        }
        for (; e < m; ++e) {
            int i0 = __shfl(idx, e);
            a += __uint_as_float((uint)h[(size_t)i0 * 64 + lane] << 16);
        }
    }
    float v = (c > 0) ? a / (float)c
                      : __uint_as_float((uint)h[(size_t)wid * 64 + lane] << 16);

    float m = v;
#pragma unroll
    for (int off = 32; off > 0; off >>= 1) m = fmaxf(m, __shfl_xor(m, off));
    float ex = __expf(v - m);
    float s = ex;
#pragma unroll
    for (int off = 32; off > 0; off >>= 1) s += __shfl_xor(s, off);
    out[(size_t)wid * 64 + lane] = v - m - __logf(s);
}

// ---------------------------------------------------------------------------
extern "C" void kernel_launch(void* const* d_in, const int* in_sizes, int n_in,
                              void* d_out, int out_size, void* d_ws, size_t ws_size,
                              hipStream_t stream) {
    const float* x  = (const float*)d_in[0];
    const int*   ei = (const int*)d_in[1];
    const float* W1 = (const float*)d_in[2];
    const float* b1 = (const float*)d_in[3];
    const float* W2 = (const float*)d_in[4];
    const float* b2 = (const float*)d_in[5];
    const float* W3 = (const float*)d_in[6];
    const float* b3 = (const float*)d_in[7];
    float* out = (float*)d_out;

    const int n = in_sizes[0] / 128;
    const int E = in_sizes[1] / 2;
    const int* row = ei;        // edge_index[0]
    const int* col = ei + E;    // edge_index[1]

    char* ws = (char*)d_ws;
    size_t off = 0;
    auto carve = [&](size_t bytes) {
        char* p = ws + off;
        off = (off + bytes + 255) & ~(size_t)255;
        return p;
    };
    ushort* hbuf      = (ushort*)carve((size_t)n * 128 * 2);
    ushort* abuf      = (ushort*)carve((size_t)n * 128 * 2);
    ushort* Wf2       = (ushort*)carve(4 * 8 * 64 * 8 * 2);
    ushort* Wf3       = (ushort*)carve(4 * 4 * 64 * 8 * 2);
    int*    cnt       = (int*)carve((size_t)((n + 3) / 4) * 16);
    int*    start     = (int*)carve((size_t)n * sizeof(int));
    ushort* rank16    = (ushort*)carve((size_t)E * 2);
    ushort* srclist16 = (ushort*)carve((size_t)E * 2);
    int*    bsum      = (int*)carve(1024);

    const int HB = (E + 255) / 256;          // hist / scatter blocks
    const int nb = (n + 255) / 256;          // scan blocks (<=256)
    const int nwave = (n + 15) / 16;
    const int GB    = (nwave + 3) / 4;       // gemm blocks (4 waves/block)
    const int agrid = (n + 3) / 4;           // 1 node/wave

    const int n4 = (n + 3) / 4;
    zero_cnt<<<(n4 + 255) / 256, 256, 0, stream>>>((int4*)cnt, n4);
    fused_g1_hist<<<GB + HB + 12, 256, 0, stream>>>(x, W1, b1, hbuf,
                                                    col, cnt, rank16,
                                                    W2, Wf2, W3, Wf3,
                                                    n, E, GB, HB);
    scan_partial<<<nb, 256, 0, stream>>>(cnt, bsum, n);
    scan_bsums<<<1, 256, 0, stream>>>(bsum, nb);
    scan_final<<<nb, 256, 0, stream>>>(cnt, bsum, start, n);
    scatter16<<<HB, 256, 0, stream>>>(row, col, start, rank16, srclist16, E);

    agg128_bf16<true><<<agrid, 256, 0, stream>>>(hbuf, start, cnt, srclist16, abuf, n);
    gemm_mfma<128><<<GB, 256, 0, stream>>>(abuf, Wf2, b2, hbuf, n);
    agg128_bf16<true><<<agrid, 256, 0, stream>>>(hbuf, start, cnt, srclist16, abuf, n);
    gemm_mfma<64><<<GB, 256, 0, stream>>>(abuf, Wf3, b3, hbuf, n);
    agg64_lsm_bf16<<<agrid, 256, 0, stream>>>(hbuf, start, cnt, srclist16, out, n);
}

// Round 6
// 183.062 us; speedup vs baseline: 1.8626x; 1.0162x over previous
//
#include <hip/hip_runtime.h>
#include <hip/hip_bf16.h>

// ---------------------------------------------------------------------------
// GCN: 3 x (linear -> segment-mean -> [relu]) -> log_softmax
// R6: histogram atomics were line-serialization-bound (~256 RMW/line,
//     ~175ns each => 45us). 8 XCD-aligned replicas (rep = blockIdx&7,
//     replica-major layout so no line is shared across replicas) cut
//     per-line ops 8x and pin line ownership to one XCD under the default
//     round-robin mapping. rank16 packs (rep<<12)|rank. Scan absorbs the
//     replicas: scan_partial sums 8 replicas inline; scan_final also emits
//     baseR[rep*n+node]. Correct for ANY block->XCD mapping.
// NOTE: assumes n < 65536 (problem fixes N=50000).
// ---------------------------------------------------------------------------

typedef __attribute__((ext_vector_type(8))) short short8v;
typedef __attribute__((ext_vector_type(4))) float f32x4;

static __device__ __forceinline__ ushort f2bf(float f) {
    __hip_bfloat16 h = __float2bfloat16(f);   // RNE
    return *reinterpret_cast<ushort*>(&h);
}
static __device__ __forceinline__ float bf_lo(uint u) { return __uint_as_float(u << 16); }
static __device__ __forceinline__ float bf_hi(uint u) { return __uint_as_float(u & 0xffff0000u); }

// ------------------------------ zero kernel --------------------------------
__global__ __launch_bounds__(256) void zero_cnt(int4* __restrict__ p, int n4) {
    int i = blockIdx.x * 256 + threadIdx.x;
    if (i < n4) p[i] = make_int4(0, 0, 0, 0);
}

// ------------------------- GEMM1 body (fp32 sources) -----------------------
static __device__ __forceinline__ void gemm1_body(
    const float* __restrict__ X, const float* __restrict__ W,
    const float* __restrict__ bias, ushort* __restrict__ Y, int n,
    int wid, int lane) {
    int r0 = wid * 16;
    if (r0 >= n) return;
    int arow = r0 + (lane & 15);
    if (arow >= n) arow = n - 1;
    int kb = lane >> 4;
    int c  = lane & 15;

    f32x4 acc[8];
#pragma unroll
    for (int ct = 0; ct < 8; ++ct) acc[ct] = (f32x4)(0.f);

#pragma unroll
    for (int kt = 0; kt < 4; ++kt) {
        const float* ap = &X[(size_t)arow * 128 + kt * 32 + kb * 8];
        float4 a0 = *(const float4*)ap;
        float4 a1 = *(const float4*)(ap + 4);
        union { short8v v; ushort u[8]; } av;
        av.u[0] = f2bf(a0.x); av.u[1] = f2bf(a0.y);
        av.u[2] = f2bf(a0.z); av.u[3] = f2bf(a0.w);
        av.u[4] = f2bf(a1.x); av.u[5] = f2bf(a1.y);
        av.u[6] = f2bf(a1.z); av.u[7] = f2bf(a1.w);
#pragma unroll
        for (int ct = 0; ct < 8; ++ct) {
            union { short8v v; ushort u[8]; } bv;
#pragma unroll
            for (int j = 0; j < 8; ++j)
                bv.u[j] = f2bf(W[(size_t)(kt * 32 + kb * 8 + j) * 128 + ct * 16 + c]);
            acc[ct] = __builtin_amdgcn_mfma_f32_16x16x32_bf16(av.v, bv.v, acc[ct], 0, 0, 0);
        }
    }

    int rg = lane >> 4;
#pragma unroll
    for (int ct = 0; ct < 8; ++ct) {
        float bvs = bias[ct * 16 + c];
#pragma unroll
        for (int j = 0; j < 4; ++j) {
            int r = r0 + rg * 4 + j;
            if (r < n) Y[(size_t)r * 128 + ct * 16 + c] = f2bf(acc[ct][j] + bvs);
        }
    }
}

// ------------- fused: gemm1 | hist(8 replicas)+rank | repack ---------------
__global__ __launch_bounds__(256) void fused_g1_hist(
    const float* __restrict__ x, const float* __restrict__ W1,
    const float* __restrict__ b1, ushort* __restrict__ hbuf,
    const int* __restrict__ col, int* __restrict__ cntV, ushort* __restrict__ rank16,
    const float* __restrict__ W2, ushort* __restrict__ Wf2,
    const float* __restrict__ W3, ushort* __restrict__ Wf3,
    int n, int E, int GB, int HB) {
    int braw = blockIdx.x;
    int b = braw, t = threadIdx.x;
    if (b < GB) {
        int wid = (b * 256 + t) >> 6;
        gemm1_body(x, W1, b1, hbuf, n, wid, t & 63);
        return;
    }
    b -= GB;
    if (b < HB) {
        int e = b * 256 + t;
        if (e < E) {
            int rep = braw & 7;   // matches default round-robin block->XCD map
            int r = atomicAdd(&cntV[rep * n + col[e]], 1);
            rank16[e] = (ushort)((rep << 12) | r);
        }
        return;
    }
    b -= HB;
    // repack: W2 blocks [0,8), W3 blocks [8,12)
    const float* W; ushort* Wf; int OUT; int tid;
    if (b < 8) { W = W2; Wf = Wf2; OUT = 128; tid = b * 256 + t; }
    else       { W = W3; Wf = Wf3; OUT = 64;  tid = (b - 8) * 256 + t; }
    int CT = OUT >> 4;
    int total = 4 * CT * 64;
    if (tid >= total) return;
    int kt   = tid / (CT * 64);
    int rem  = tid % (CT * 64);
    int ct   = rem >> 6;
    int lane = rem & 63;
    int c  = lane & 15;
    int kb = lane >> 4;
    ushort tmp[8];
#pragma unroll
    for (int j = 0; j < 8; ++j)
        tmp[j] = f2bf(W[(kt * 32 + kb * 8 + j) * OUT + ct * 16 + c]);
    uint4 o;
    o.x = ((uint)tmp[1] << 16) | tmp[0];
    o.y = ((uint)tmp[3] << 16) | tmp[2];
    o.z = ((uint)tmp[5] << 16) | tmp[4];
    o.w = ((uint)tmp[7] << 16) | tmp[6];
    ((uint4*)Wf)[tid] = o;
}

// --------------------- scan (8-replica cnt -> start, baseR) ----------------
// scan_partial: tot[i] = sum_r cntV[r*n+i]; block-sums to bsum.
__global__ void scan_partial(const int* __restrict__ cntV, int* __restrict__ tot,
                             int* __restrict__ bsum, int n) {
    __shared__ int lds[256];
    int i = blockIdx.x * 256 + threadIdx.x;
    int v = 0;
    if (i < n) {
#pragma unroll
        for (int r = 0; r < 8; ++r) v += cntV[r * n + i];
        tot[i] = v;
    }
    lds[threadIdx.x] = v;
    __syncthreads();
    for (int s = 128; s > 0; s >>= 1) {
        if (threadIdx.x < s) lds[threadIdx.x] += lds[threadIdx.x + s];
        __syncthreads();
    }
    if (threadIdx.x == 0) bsum[blockIdx.x] = lds[0];
}

__global__ void scan_bsums(int* __restrict__ bsum, int nb) {
    __shared__ int lds[256];
    int t = threadIdx.x;
    int v = (t < nb) ? bsum[t] : 0;
    lds[t] = v;
    __syncthreads();
    for (int off = 1; off < 256; off <<= 1) {
        int u = (t >= off) ? lds[t - off] : 0;
        __syncthreads();
        lds[t] += u;
        __syncthreads();
    }
    if (t < nb) bsum[t] = lds[t] - v;  // exclusive
}

// scan_final: start[i] (exclusive over tot) + baseR[r*n+i] replica bases.
__global__ void scan_final(const int* __restrict__ tot, const int* __restrict__ bsum,
                           const int* __restrict__ cntV, int* __restrict__ start,
                           int* __restrict__ baseR, int n) {
    __shared__ int lds[256];
    int t = threadIdx.x;
    int i = blockIdx.x * 256 + t;
    int v = (i < n) ? tot[i] : 0;
    lds[t] = v;
    __syncthreads();
    for (int off = 1; off < 256; off <<= 1) {
        int u = (t >= off) ? lds[t - off] : 0;
        __syncthreads();
        lds[t] += u;
        __syncthreads();
    }
    if (i < n) {
        int acc = lds[t] - v + bsum[blockIdx.x];
        start[i] = acc;
#pragma unroll
        for (int r = 0; r < 8; ++r) {
            baseR[r * n + i] = acc;
            acc += cntV[r * n + i];
        }
    }
}

// ------------------------- atomic-free scatter -----------------------------
__global__ __launch_bounds__(256) void scatter16(
    const int* __restrict__ row, const int* __restrict__ col,
    const int* __restrict__ baseR, const ushort* __restrict__ rank16,
    ushort* __restrict__ srclist16, int n, int E) {
    int e = blockIdx.x * 256 + threadIdx.x;
    if (e < E) {
        int d = col[e];
        uint pk = rank16[e];
        int rep = pk >> 12;
        int r   = pk & 0xFFF;
        srclist16[baseR[rep * n + d] + r] = (ushort)row[e];
    }
}

// ------------------------------- MFMA GEMM (bf16 src) ----------------------
template <int OUT>
__global__ __launch_bounds__(256) void gemm_mfma(
    const ushort* __restrict__ X, const ushort* __restrict__ Wf,
    const float* __restrict__ bias, ushort* __restrict__ Y, int n) {
    constexpr int CT = OUT / 16;
    int wid  = (blockIdx.x * 256 + threadIdx.x) >> 6;
    int lane = threadIdx.x & 63;
    int r0 = wid * 16;
    if (r0 >= n) return;
    int arow = r0 + (lane & 15);
    if (arow >= n) arow = n - 1;
    int kb = lane >> 4;

    f32x4 acc[CT];
#pragma unroll
    for (int ct = 0; ct < CT; ++ct) acc[ct] = (f32x4)(0.f);

#pragma unroll
    for (int kt = 0; kt < 4; ++kt) {
        short8v a = *(const short8v*)&X[(size_t)arow * 128 + kt * 32 + kb * 8];
#pragma unroll
        for (int ct = 0; ct < CT; ++ct) {
            short8v b = *(const short8v*)&Wf[(size_t)((kt * CT + ct) * 64 + lane) * 8];
            acc[ct] = __builtin_amdgcn_mfma_f32_16x16x32_bf16(a, b, acc[ct], 0, 0, 0);
        }
    }

    int c  = lane & 15;
    int rg = lane >> 4;
#pragma unroll
    for (int ct = 0; ct < CT; ++ct) {
        float bv = bias[ct * 16 + c];
#pragma unroll
        for (int j = 0; j < 4; ++j) {
            int r = r0 + rg * 4 + j;
            if (r < n) Y[(size_t)r * OUT + ct * 16 + c] = f2bf(acc[ct][j] + bv);
        }
    }
}

// ------------------------------ aggregation --------------------------------
template <bool RELU>
__global__ __launch_bounds__(256) void agg128_bf16(
    const ushort* __restrict__ h, const int* __restrict__ start,
    const int* __restrict__ cnt, const ushort* __restrict__ srclist16,
    ushort* __restrict__ out, int n) {
    int wid  = (blockIdx.x * blockDim.x + threadIdx.x) >> 6;
    int lane = threadIdx.x & 63;
    if (wid >= n) return;
    const uint* h32 = (const uint*)h;   // [n][64] dwords
    int s0 = start[wid];
    int c  = cnt[wid];
    float ax = 0.f, ay = 0.f;
    for (int base = 0; base < c; base += 64) {
        int m = c - base;
        if (m > 64) m = 64;
        int idx = (int)srclist16[s0 + base + (lane < m ? lane : 0)];
        int e = 0;
        for (; e + 8 <= m; e += 8) {
            int i0 = __shfl(idx, e + 0), i1 = __shfl(idx, e + 1);
            int i2 = __shfl(idx, e + 2), i3 = __shfl(idx, e + 3);
            int i4 = __shfl(idx, e + 4), i5 = __shfl(idx, e + 5);
            int i6 = __shfl(idx, e + 6), i7 = __shfl(idx, e + 7);
            uint u0 = h32[(size_t)i0 * 64 + lane];
            uint u1 = h32[(size_t)i1 * 64 + lane];
            uint u2 = h32[(size_t)i2 * 64 + lane];
            uint u3 = h32[(size_t)i3 * 64 + lane];
            uint u4 = h32[(size_t)i4 * 64 + lane];
            uint u5 = h32[(size_t)i5 * 64 + lane];
            uint u6 = h32[(size_t)i6 * 64 + lane];
            uint u7 = h32[(size_t)i7 * 64 + lane];
            ax += ((bf_lo(u0) + bf_lo(u1)) + (bf_lo(u2) + bf_lo(u3))) +
                  ((bf_lo(u4) + bf_lo(u5)) + (bf_lo(u6) + bf_lo(u7)));
            ay += ((bf_hi(u0) + bf_hi(u1)) + (bf_hi(u2) + bf_hi(u3))) +
                  ((bf_hi(u4) + bf_hi(u5)) + (bf_hi(u6) + bf_hi(u7)));
        }
        for (; e + 4 <= m; e += 4) {
            int i0 = __shfl(idx, e + 0), i1 = __shfl(idx, e + 1);
            int i2 = __shfl(idx, e + 2), i3 = __shfl(idx, e + 3);
            uint u0 = h32[(size_t)i0 * 64 + lane];
            uint u1 = h32[(size_t)i1 * 64 + lane];
            uint u2 = h32[(size_t)i2 * 64 + lane];
            uint u3 = h32[(size_t)i3 * 64 + lane];
            ax += (bf_lo(u0) + bf_lo(u1)) + (bf_lo(u2) + bf_lo(u3));
            ay += (bf_hi(u0) + bf_hi(u1)) + (bf_hi(u2) + bf_hi(u3));
        }
        for (; e < m; ++e) {
            int i0 = __shfl(idx, e);
            uint u0 = h32[(size_t)i0 * 64 + lane];
            ax += bf_lo(u0);
            ay += bf_hi(u0);
        }
    }
    float rx, ry;
    if (c > 0) {
        float inv = 1.f / (float)c;
        rx = ax * inv; ry = ay * inv;
    } else {
        uint u = h32[(size_t)wid * 64 + lane];
        rx = bf_lo(u); ry = bf_hi(u);
    }
    if (RELU) { rx = fmaxf(rx, 0.f); ry = fmaxf(ry, 0.f); }
    ((uint*)out)[(size_t)wid * 64 + lane] = ((uint)f2bf(ry) << 16) | f2bf(rx);
}

// D=64 final layer: lane owns 1 bf16; fused log_softmax; fp32 output.
__global__ __launch_bounds__(256) void agg64_lsm_bf16(
    const ushort* __restrict__ h, const int* __restrict__ start,
    const int* __restrict__ cnt, const ushort* __restrict__ srclist16,
    float* __restrict__ out, int n) {
    int wid  = (blockIdx.x * blockDim.x + threadIdx.x) >> 6;
    int lane = threadIdx.x & 63;
    if (wid >= n) return;
    int s0 = start[wid];
    int c  = cnt[wid];
    float a = 0.f;
    for (int base = 0; base < c; base += 64) {
        int m = c - base;
        if (m > 64) m = 64;
        int idx = (int)srclist16[s0 + base + (lane < m ? lane : 0)];
        int e = 0;
        for (; e + 8 <= m; e += 8) {
            int i0 = __shfl(idx, e + 0), i1 = __shfl(idx, e + 1);
            int i2 = __shfl(idx, e + 2), i3 = __shfl(idx, e + 3);
            int i4 = __shfl(idx, e + 4), i5 = __shfl(idx, e + 5);
            int i6 = __shfl(idx, e + 6), i7 = __shfl(idx, e + 7);
            float v0 = __uint_as_float((uint)h[(size_t)i0 * 64 + lane] << 16);
            float v1 = __uint_as_float((uint)h[(size_t)i1 * 64 + lane] << 16);
            float v2 = __uint_as_float((uint)h[(size_t)i2 * 64 + lane] << 16);
            float v3 = __uint_as_float((uint)h[(size_t)i3 * 64 + lane] << 16);
            float v4 = __uint_as_float((uint)h[(size_t)i4 * 64 + lane] << 16);
            float v5 = __uint_as_float((uint)h[(size_t)i5 * 64 + lane] << 16);
            float v6 = __uint_as_float((uint)h[(size_t)i6 * 64 + lane] << 16);
            float v7 = __uint_as_float((uint)h[(size_t)i7 * 64 + lane] << 16);
            a += ((v0 + v1) + (v2 + v3)) + ((v4 + v5) + (v6 + v7));
        }
        for (; e < m; ++e) {
            int i0 = __shfl(idx, e);
            a += __uint_as_float((uint)h[(size_t)i0 * 64 + lane] << 16);
        }
    }
    float v = (c > 0) ? a / (float)c
                      : __uint_as_float((uint)h[(size_t)wid * 64 + lane] << 16);

    float m = v;
#pragma unroll
    for (int off = 32; off > 0; off >>= 1) m = fmaxf(m, __shfl_xor(m, off));
    float ex = __expf(v - m);
    float s = ex;
#pragma unroll
    for (int off = 32; off > 0; off >>= 1) s += __shfl_xor(s, off);
    out[(size_t)wid * 64 + lane] = v - m - __logf(s);
}

// ---------------------------------------------------------------------------
extern "C" void kernel_launch(void* const* d_in, const int* in_sizes, int n_in,
                              void* d_out, int out_size, void* d_ws, size_t ws_size,
                              hipStream_t stream) {
    const float* x  = (const float*)d_in[0];
    const int*   ei = (const int*)d_in[1];
    const float* W1 = (const float*)d_in[2];
    const float* b1 = (const float*)d_in[3];
    const float* W2 = (const float*)d_in[4];
    const float* b2 = (const float*)d_in[5];
    const float* W3 = (const float*)d_in[6];
    const float* b3 = (const float*)d_in[7];
    float* out = (float*)d_out;

    const int n = in_sizes[0] / 128;
    const int E = in_sizes[1] / 2;
    const int* row = ei;        // edge_index[0]
    const int* col = ei + E;    // edge_index[1]

    char* ws = (char*)d_ws;
    size_t off = 0;
    auto carve = [&](size_t bytes) {
        char* p = ws + off;
        off = (off + bytes + 255) & ~(size_t)255;
        return p;
    };
    ushort* hbuf      = (ushort*)carve((size_t)n * 128 * 2);
    ushort* abuf      = (ushort*)carve((size_t)n * 128 * 2);
    ushort* Wf2       = (ushort*)carve(4 * 8 * 64 * 8 * 2);
    ushort* Wf3       = (ushort*)carve(4 * 4 * 64 * 8 * 2);
    int*    cntV      = (int*)carve((size_t)8 * n * sizeof(int));   // 8 replicas
    int*    baseR     = (int*)carve((size_t)8 * n * sizeof(int));
    int*    tot       = (int*)carve((size_t)n * sizeof(int));
    int*    start     = (int*)carve((size_t)n * sizeof(int));
    ushort* rank16    = (ushort*)carve((size_t)E * 2);
    ushort* srclist16 = (ushort*)carve((size_t)E * 2);
    int*    bsum      = (int*)carve(1024);

    const int HB = (E + 255) / 256;          // hist / scatter blocks
    const int nb = (n + 255) / 256;          // scan blocks (<=256)
    const int nwave = (n + 15) / 16;
    const int GB    = (nwave + 3) / 4;       // gemm blocks (4 waves/block)
    const int agrid = (n + 3) / 4;           // 1 node/wave

    const int z4 = (8 * n + 3) / 4;
    zero_cnt<<<(z4 + 255) / 256, 256, 0, stream>>>((int4*)cntV, z4);
    fused_g1_hist<<<GB + HB + 12, 256, 0, stream>>>(x, W1, b1, hbuf,
                                                    col, cntV, rank16,
                                                    W2, Wf2, W3, Wf3,
                                                    n, E, GB, HB);
    scan_partial<<<nb, 256, 0, stream>>>(cntV, tot, bsum, n);
    scan_bsums<<<1, 256, 0, stream>>>(bsum, nb);
    scan_final<<<nb, 256, 0, stream>>>(tot, bsum, cntV, start, baseR, n);
    scatter16<<<HB, 256, 0, stream>>>(row, col, baseR, rank16, srclist16, n, E);

    agg128_bf16<true><<<agrid, 256, 0, stream>>>(hbuf, start, tot, srclist16, abuf, n);
    gemm_mfma<128><<<GB, 256, 0, stream>>>(abuf, Wf2, b2, hbuf, n);
    agg128_bf16<true><<<agrid, 256, 0, stream>>>(hbuf, start, tot, srclist16, abuf, n);
    gemm_mfma<64><<<GB, 256, 0, stream>>>(abuf, Wf3, b3, hbuf, n);
    agg64_lsm_bf16<<<agrid, 256, 0, stream>>>(hbuf, start, tot, srclist16, out, n);
}

// Round 7
// 168.255 us; speedup vs baseline: 2.0265x; 1.0880x over previous
//
#include <hip/hip_runtime.h>
#include <hip/hip_bf16.h>

// ---------------------------------------------------------------------------
// GCN: 3 x (linear -> segment-mean -> [relu]) -> log_softmax
// R7: global-atomic histogram hit a ~18G atomics/s per-op ceiling (45us,
//     replication null-result R6). CSR build rewritten as a two-level
//     LDS-atomic counting sort: PA coarse hist (256 partitions x 782
//     buckets of 64 nodes) -> Gmat scan -> PA2 coarse scatter (packed
//     (d&63,src) pairs, slots from LDS cursors) -> PB per-bucket fine CSR.
//     Zero global atomics. Downstream agg/gemm unchanged.
// NOTE: assumes n <= 65536 (problem fixes N=50000).
// ---------------------------------------------------------------------------

typedef __attribute__((ext_vector_type(8))) short short8v;
typedef __attribute__((ext_vector_type(4))) float f32x4;

#define NPART 256   // coarse partitions (blocks) in PA/PA2

static __device__ __forceinline__ ushort f2bf(float f) {
    __hip_bfloat16 h = __float2bfloat16(f);   // RNE
    return *reinterpret_cast<ushort*>(&h);
}
static __device__ __forceinline__ float bf_lo(uint u) { return __uint_as_float(u << 16); }
static __device__ __forceinline__ float bf_hi(uint u) { return __uint_as_float(u & 0xffff0000u); }

// ------------------------- GEMM1 body (fp32 sources) -----------------------
static __device__ __forceinline__ void gemm1_body(
    const float* __restrict__ X, const float* __restrict__ W,
    const float* __restrict__ bias, ushort* __restrict__ Y, int n,
    int wid, int lane) {
    int r0 = wid * 16;
    if (r0 >= n) return;
    int arow = r0 + (lane & 15);
    if (arow >= n) arow = n - 1;
    int kb = lane >> 4;
    int c  = lane & 15;

    f32x4 acc[8];
#pragma unroll
    for (int ct = 0; ct < 8; ++ct) acc[ct] = (f32x4)(0.f);

#pragma unroll
    for (int kt = 0; kt < 4; ++kt) {
        const float* ap = &X[(size_t)arow * 128 + kt * 32 + kb * 8];
        float4 a0 = *(const float4*)ap;
        float4 a1 = *(const float4*)(ap + 4);
        union { short8v v; ushort u[8]; } av;
        av.u[0] = f2bf(a0.x); av.u[1] = f2bf(a0.y);
        av.u[2] = f2bf(a0.z); av.u[3] = f2bf(a0.w);
        av.u[4] = f2bf(a1.x); av.u[5] = f2bf(a1.y);
        av.u[6] = f2bf(a1.z); av.u[7] = f2bf(a1.w);
#pragma unroll
        for (int ct = 0; ct < 8; ++ct) {
            union { short8v v; ushort u[8]; } bv;
#pragma unroll
            for (int j = 0; j < 8; ++j)
                bv.u[j] = f2bf(W[(size_t)(kt * 32 + kb * 8 + j) * 128 + ct * 16 + c]);
            acc[ct] = __builtin_amdgcn_mfma_f32_16x16x32_bf16(av.v, bv.v, acc[ct], 0, 0, 0);
        }
    }

    int rg = lane >> 4;
#pragma unroll
    for (int ct = 0; ct < 8; ++ct) {
        float bvs = bias[ct * 16 + c];
#pragma unroll
        for (int j = 0; j < 4; ++j) {
            int r = r0 + rg * 4 + j;
            if (r < n) Y[(size_t)r * 128 + ct * 16 + c] = f2bf(acc[ct][j] + bvs);
        }
    }
}

// -------- fused PA: coarse LDS hist (NPART blocks) | gemm1 | repack --------
__global__ __launch_bounds__(256) void fused_pa(
    const int* __restrict__ col, int* __restrict__ Gmat,
    const float* __restrict__ x, const float* __restrict__ W1,
    const float* __restrict__ b1, ushort* __restrict__ hbuf,
    const float* __restrict__ W2, ushort* __restrict__ Wf2,
    const float* __restrict__ W3, ushort* __restrict__ Wf3,
    int n, int E, int NBKT, int ECH, int GB) {
    __shared__ uint hist[1024];
    int b = blockIdx.x, t = threadIdx.x;
    if (b < NPART) {
        for (int i = t; i < NBKT; i += 256) hist[i] = 0;
        __syncthreads();
        int e0 = b * ECH, e1 = min(e0 + ECH, E);
        for (int e = e0 + t; e < e1; e += 256)
            atomicAdd(&hist[col[e] >> 6], 1u);
        __syncthreads();
        for (int i = t; i < NBKT; i += 256)
            Gmat[i * NPART + b] = (int)hist[i];
        return;
    }
    b -= NPART;
    if (b < GB) {
        int wid = (b * 256 + t) >> 6;
        gemm1_body(x, W1, b1, hbuf, n, wid, t & 63);
        return;
    }
    b -= GB;
    // repack: W2 blocks [0,8), W3 blocks [8,12)
    const float* W; ushort* Wf; int OUT; int tid;
    if (b < 8) { W = W2; Wf = Wf2; OUT = 128; tid = b * 256 + t; }
    else       { W = W3; Wf = Wf3; OUT = 64;  tid = (b - 8) * 256 + t; }
    int CT = OUT >> 4;
    int total = 4 * CT * 64;
    if (tid >= total) return;
    int kt   = tid / (CT * 64);
    int rem  = tid % (CT * 64);
    int ct   = rem >> 6;
    int lane = rem & 63;
    int c  = lane & 15;
    int kb = lane >> 4;
    ushort tmp[8];
#pragma unroll
    for (int j = 0; j < 8; ++j)
        tmp[j] = f2bf(W[(kt * 32 + kb * 8 + j) * OUT + ct * 16 + c]);
    uint4 o;
    o.x = ((uint)tmp[1] << 16) | tmp[0];
    o.y = ((uint)tmp[3] << 16) | tmp[2];
    o.z = ((uint)tmp[5] << 16) | tmp[4];
    o.w = ((uint)tmp[7] << 16) | tmp[6];
    ((uint4*)Wf)[tid] = o;
}

// ----------------- scan of flat Gmat (M = NBKT*NPART entries) --------------
__global__ void scanA_partial(const int* __restrict__ g, int* __restrict__ bsum, int M) {
    __shared__ int lds[256];
    int i = blockIdx.x * 256 + threadIdx.x;
    int v = (i < M) ? g[i] : 0;
    lds[threadIdx.x] = v;
    __syncthreads();
    for (int s = 128; s > 0; s >>= 1) {
        if (threadIdx.x < s) lds[threadIdx.x] += lds[threadIdx.x + s];
        __syncthreads();
    }
    if (threadIdx.x == 0) bsum[blockIdx.x] = lds[0];
}

// single block; nb <= 1024; exclusive scan in place
__global__ void scan_bsums_big(int* __restrict__ bsum, int nb) {
    __shared__ int ts[256];
    int t = threadIdx.x;
    int v[4]; int s = 0;
#pragma unroll
    for (int j = 0; j < 4; ++j) {
        int i = t * 4 + j;
        v[j] = (i < nb) ? bsum[i] : 0;
        s += v[j];
    }
    ts[t] = s;
    __syncthreads();
    for (int off = 1; off < 256; off <<= 1) {
        int u = (t >= off) ? ts[t - off] : 0;
        __syncthreads();
        ts[t] += u;
        __syncthreads();
    }
    int run = ts[t] - s;   // exclusive base for this thread's 4
#pragma unroll
    for (int j = 0; j < 4; ++j) {
        int i = t * 4 + j;
        if (i < nb) { int old = v[j]; bsum[i] = run; run += old; }
    }
}

__global__ void scanA_final(int* __restrict__ g, const int* __restrict__ bsum, int M) {
    __shared__ int lds[256];
    int t = threadIdx.x;
    int i = blockIdx.x * 256 + t;
    int v = (i < M) ? g[i] : 0;
    lds[t] = v;
    __syncthreads();
    for (int off = 1; off < 256; off <<= 1) {
        int u = (t >= off) ? lds[t - off] : 0;
        __syncthreads();
        lds[t] += u;
        __syncthreads();
    }
    if (i < M) g[i] = lds[t] - v + bsum[blockIdx.x];   // exclusive
}

// ------------------- PA2: coarse scatter (LDS cursors) ---------------------
__global__ __launch_bounds__(256) void pa2_scatter(
    const int* __restrict__ row, const int* __restrict__ col,
    const int* __restrict__ Gscan, uint* __restrict__ coarse,
    int E, int NBKT, int ECH) {
    __shared__ uint cur[1024];
    int p = blockIdx.x, t = threadIdx.x;
    for (int i = t; i < NBKT; i += 256) cur[i] = (uint)Gscan[i * NPART + p];
    __syncthreads();
    int e0 = p * ECH, e1 = min(e0 + ECH, E);
    for (int e = e0 + t; e < e1; e += 256) {
        int d = col[e];
        uint slot = atomicAdd(&cur[d >> 6], 1u);
        coarse[slot] = ((uint)(d & 63) << 16) | (uint)(row[e] & 0xFFFF);
    }
}

// ---------------- PB: per-bucket fine CSR (64 nodes/bucket) ----------------
__global__ __launch_bounds__(256) void pb_fine(
    const uint* __restrict__ coarse, const int* __restrict__ Gscan,
    int* __restrict__ cnt, int* __restrict__ start,
    ushort* __restrict__ srclist16, int n, int E, int NBKT) {
    __shared__ uint c64[64];
    int b = blockIdx.x, t = threadIdx.x;
    int lo = Gscan[b * NPART];
    int hi = (b + 1 < NBKT) ? Gscan[(b + 1) * NPART] : E;
    if (t < 64) c64[t] = 0;
    __syncthreads();
    for (int i = lo + t; i < hi; i += 256)
        atomicAdd(&c64[coarse[i] >> 16], 1u);
    __syncthreads();
    if (t < 64) {
        uint v = c64[t];
        uint x = v;
#pragma unroll
        for (int off = 1; off < 64; off <<= 1) {
            uint u = __shfl_up(x, off);
            if (t >= off) x += u;
        }
        uint excl = x - v;
        int node = b * 64 + t;
        if (node < n) { cnt[node] = (int)v; start[node] = lo + (int)excl; }
        c64[t] = excl;   // becomes intra-bucket cursor
    }
    __syncthreads();
    for (int i = lo + t; i < hi; i += 256) {
        uint u  = coarse[i];
        uint dl = u >> 16;
        uint slot = atomicAdd(&c64[dl], 1u);
        srclist16[lo + slot] = (ushort)u;
    }
}

// ------------------------------- MFMA GEMM (bf16 src) ----------------------
template <int OUT>
__global__ __launch_bounds__(256) void gemm_mfma(
    const ushort* __restrict__ X, const ushort* __restrict__ Wf,
    const float* __restrict__ bias, ushort* __restrict__ Y, int n) {
    constexpr int CT = OUT / 16;
    int wid  = (blockIdx.x * 256 + threadIdx.x) >> 6;
    int lane = threadIdx.x & 63;
    int r0 = wid * 16;
    if (r0 >= n) return;
    int arow = r0 + (lane & 15);
    if (arow >= n) arow = n - 1;
    int kb = lane >> 4;

    f32x4 acc[CT];
#pragma unroll
    for (int ct = 0; ct < CT; ++ct) acc[ct] = (f32x4)(0.f);

#pragma unroll
    for (int kt = 0; kt < 4; ++kt) {
        short8v a = *(const short8v*)&X[(size_t)arow * 128 + kt * 32 + kb * 8];
#pragma unroll
        for (int ct = 0; ct < CT; ++ct) {
            short8v b = *(const short8v*)&Wf[(size_t)((kt * CT + ct) * 64 + lane) * 8];
            acc[ct] = __builtin_amdgcn_mfma_f32_16x16x32_bf16(a, b, acc[ct], 0, 0, 0);
        }
    }

    int c  = lane & 15;
    int rg = lane >> 4;
#pragma unroll
    for (int ct = 0; ct < CT; ++ct) {
        float bv = bias[ct * 16 + c];
#pragma unroll
        for (int j = 0; j < 4; ++j) {
            int r = r0 + rg * 4 + j;
            if (r < n) Y[(size_t)r * OUT + ct * 16 + c] = f2bf(acc[ct][j] + bv);
        }
    }
}

// ------------------------------ aggregation --------------------------------
template <bool RELU>
__global__ __launch_bounds__(256) void agg128_bf16(
    const ushort* __restrict__ h, const int* __restrict__ start,
    const int* __restrict__ cnt, const ushort* __restrict__ srclist16,
    ushort* __restrict__ out, int n) {
    int wid  = (blockIdx.x * blockDim.x + threadIdx.x) >> 6;
    int lane = threadIdx.x & 63;
    if (wid >= n) return;
    const uint* h32 = (const uint*)h;   // [n][64] dwords
    int s0 = start[wid];
    int c  = cnt[wid];
    float ax = 0.f, ay = 0.f;
    for (int base = 0; base < c; base += 64) {
        int m = c - base;
        if (m > 64) m = 64;
        int idx = (int)srclist16[s0 + base + (lane < m ? lane : 0)];
        int e = 0;
        for (; e + 8 <= m; e += 8) {
            int i0 = __shfl(idx, e + 0), i1 = __shfl(idx, e + 1);
            int i2 = __shfl(idx, e + 2), i3 = __shfl(idx, e + 3);
            int i4 = __shfl(idx, e + 4), i5 = __shfl(idx, e + 5);
            int i6 = __shfl(idx, e + 6), i7 = __shfl(idx, e + 7);
            uint u0 = h32[(size_t)i0 * 64 + lane];
            uint u1 = h32[(size_t)i1 * 64 + lane];
            uint u2 = h32[(size_t)i2 * 64 + lane];
            uint u3 = h32[(size_t)i3 * 64 + lane];
            uint u4 = h32[(size_t)i4 * 64 + lane];
            uint u5 = h32[(size_t)i5 * 64 + lane];
            uint u6 = h32[(size_t)i6 * 64 + lane];
            uint u7 = h32[(size_t)i7 * 64 + lane];
            ax += ((bf_lo(u0) + bf_lo(u1)) + (bf_lo(u2) + bf_lo(u3))) +
                  ((bf_lo(u4) + bf_lo(u5)) + (bf_lo(u6) + bf_lo(u7)));
            ay += ((bf_hi(u0) + bf_hi(u1)) + (bf_hi(u2) + bf_hi(u3))) +
                  ((bf_hi(u4) + bf_hi(u5)) + (bf_hi(u6) + bf_hi(u7)));
        }
        for (; e + 4 <= m; e += 4) {
            int i0 = __shfl(idx, e + 0), i1 = __shfl(idx, e + 1);
            int i2 = __shfl(idx, e + 2), i3 = __shfl(idx, e + 3);
            uint u0 = h32[(size_t)i0 * 64 + lane];
            uint u1 = h32[(size_t)i1 * 64 + lane];
            uint u2 = h32[(size_t)i2 * 64 + lane];
            uint u3 = h32[(size_t)i3 * 64 + lane];
            ax += (bf_lo(u0) + bf_lo(u1)) + (bf_lo(u2) + bf_lo(u3));
            ay += (bf_hi(u0) + bf_hi(u1)) + (bf_hi(u2) + bf_hi(u3));
        }
        for (; e < m; ++e) {
            int i0 = __shfl(idx, e);
            uint u0 = h32[(size_t)i0 * 64 + lane];
            ax += bf_lo(u0);
            ay += bf_hi(u0);
        }
    }
    float rx, ry;
    if (c > 0) {
        float inv = 1.f / (float)c;
        rx = ax * inv; ry = ay * inv;
    } else {
        uint u = h32[(size_t)wid * 64 + lane];
        rx = bf_lo(u); ry = bf_hi(u);
    }
    if (RELU) { rx = fmaxf(rx, 0.f); ry = fmaxf(ry, 0.f); }
    ((uint*)out)[(size_t)wid * 64 + lane] = ((uint)f2bf(ry) << 16) | f2bf(rx);
}

// D=64 final layer: lane owns 1 bf16; fused log_softmax; fp32 output.
__global__ __launch_bounds__(256) void agg64_lsm_bf16(
    const ushort* __restrict__ h, const int* __restrict__ start,
    const int* __restrict__ cnt, const ushort* __restrict__ srclist16,
    float* __restrict__ out, int n) {
    int wid  = (blockIdx.x * blockDim.x + threadIdx.x) >> 6;
    int lane = threadIdx.x & 63;
    if (wid >= n) return;
    int s0 = start[wid];
    int c  = cnt[wid];
    float a = 0.f;
    for (int base = 0; base < c; base += 64) {
        int m = c - base;
        if (m > 64) m = 64;
        int idx = (int)srclist16[s0 + base + (lane < m ? lane : 0)];
        int e = 0;
        for (; e + 8 <= m; e += 8) {
            int i0 = __shfl(idx, e + 0), i1 = __shfl(idx, e + 1);
            int i2 = __shfl(idx, e + 2), i3 = __shfl(idx, e + 3);
            int i4 = __shfl(idx, e + 4), i5 = __shfl(idx, e + 5);
            int i6 = __shfl(idx, e + 6), i7 = __shfl(idx, e + 7);
            float v0 = __uint_as_float((uint)h[(size_t)i0 * 64 + lane] << 16);
            float v1 = __uint_as_float((uint)h[(size_t)i1 * 64 + lane] << 16);
            float v2 = __uint_as_float((uint)h[(size_t)i2 * 64 + lane] << 16);
            float v3 = __uint_as_float((uint)h[(size_t)i3 * 64 + lane] << 16);
            float v4 = __uint_as_float((uint)h[(size_t)i4 * 64 + lane] << 16);
            float v5 = __uint_as_float((uint)h[(size_t)i5 * 64 + lane] << 16);
            float v6 = __uint_as_float((uint)h[(size_t)i6 * 64 + lane] << 16);
            float v7 = __uint_as_float((uint)h[(size_t)i7 * 64 + lane] << 16);
            a += ((v0 + v1) + (v2 + v3)) + ((v4 + v5) + (v6 + v7));
        }
        for (; e < m; ++e) {
            int i0 = __shfl(idx, e);
            a += __uint_as_float((uint)h[(size_t)i0 * 64 + lane] << 16);
        }
    }
    float v = (c > 0) ? a / (float)c
                      : __uint_as_float((uint)h[(size_t)wid * 64 + lane] << 16);

    float m = v;
#pragma unroll
    for (int off = 32; off > 0; off >>= 1) m = fmaxf(m, __shfl_xor(m, off));
    float ex = __expf(v - m);
    float s = ex;
#pragma unroll
    for (int off = 32; off > 0; off >>= 1) s += __shfl_xor(s, off);
    out[(size_t)wid * 64 + lane] = v - m - __logf(s);
}

// ---------------------------------------------------------------------------
extern "C" void kernel_launch(void* const* d_in, const int* in_sizes, int n_in,
                              void* d_out, int out_size, void* d_ws, size_t ws_size,
                              hipStream_t stream) {
    const float* x  = (const float*)d_in[0];
    const int*   ei = (const int*)d_in[1];
    const float* W1 = (const float*)d_in[2];
    const float* b1 = (const float*)d_in[3];
    const float* W2 = (const float*)d_in[4];
    const float* b2 = (const float*)d_in[5];
    const float* W3 = (const float*)d_in[6];
    const float* b3 = (const float*)d_in[7];
    float* out = (float*)d_out;

    const int n = in_sizes[0] / 128;
    const int E = in_sizes[1] / 2;
    const int* row = ei;        // edge_index[0]
    const int* col = ei + E;    // edge_index[1]

    char* ws = (char*)d_ws;
    size_t off = 0;
    auto carve = [&](size_t bytes) {
        char* p = ws + off;
        off = (off + bytes + 255) & ~(size_t)255;
        return p;
    };
    ushort* hbuf      = (ushort*)carve((size_t)n * 128 * 2);
    ushort* abuf      = (ushort*)carve((size_t)n * 128 * 2);
    ushort* Wf2       = (ushort*)carve(4 * 8 * 64 * 8 * 2);
    ushort* Wf3       = (ushort*)carve(4 * 4 * 64 * 8 * 2);
    const int NBKT    = (n + 63) / 64;                       // <= 1024
    int*    Gmat      = (int*)carve((size_t)NBKT * NPART * sizeof(int));
    uint*   coarse    = (uint*)carve((size_t)E * sizeof(uint));
    int*    cnt       = (int*)carve((size_t)n * sizeof(int));
    int*    start     = (int*)carve((size_t)n * sizeof(int));
    ushort* srclist16 = (ushort*)carve((size_t)E * 2);
    int*    bsum      = (int*)carve(4096);

    const int ECH   = (E + NPART - 1) / NPART;
    const int M     = NBKT * NPART;              // flat Gmat entries
    const int MB    = (M + 255) / 256;           // = NBKT (NPART=256)
    const int nwave = (n + 15) / 16;
    const int GB    = (nwave + 3) / 4;           // gemm blocks (4 waves/block)
    const int agrid = (n + 3) / 4;               // 1 node/wave

    // CSR build (no global atomics) + gemm1 + weight repacks
    fused_pa<<<NPART + GB + 12, 256, 0, stream>>>(col, Gmat, x, W1, b1, hbuf,
                                                  W2, Wf2, W3, Wf3,
                                                  n, E, NBKT, ECH, GB);
    scanA_partial<<<MB, 256, 0, stream>>>(Gmat, bsum, M);
    scan_bsums_big<<<1, 256, 0, stream>>>(bsum, MB);
    scanA_final<<<MB, 256, 0, stream>>>(Gmat, bsum, M);
    pa2_scatter<<<NPART, 256, 0, stream>>>(row, col, Gmat, coarse, E, NBKT, ECH);
    pb_fine<<<NBKT, 256, 0, stream>>>(coarse, Gmat, cnt, start, srclist16, n, E, NBKT);

    // layers 1..3 (gemm1 already done in fused_pa)
    agg128_bf16<true><<<agrid, 256, 0, stream>>>(hbuf, start, cnt, srclist16, abuf, n);
    gemm_mfma<128><<<GB, 256, 0, stream>>>(abuf, Wf2, b2, hbuf, n);
    agg128_bf16<true><<<agrid, 256, 0, stream>>>(hbuf, start, cnt, srclist16, abuf, n);
    gemm_mfma<64><<<GB, 256, 0, stream>>>(abuf, Wf3, b3, hbuf, n);
    agg64_lsm_bf16<<<agrid, 256, 0, stream>>>(hbuf, start, cnt, srclist16, out, n);
}

// Round 9
// 149.927 us; speedup vs baseline: 2.2742x; 1.1222x over previous
//
#include <hip/hip_runtime.h>
#include <hip/hip_bf16.h>

// ---------------------------------------------------------------------------
// GCN: 3 x (linear -> segment-mean -> [relu]) -> log_softmax
// R9: R8's fused agg+gemm had an A-fragment indexing bug: tile[] is
//     dword-indexed, so a 32-bf16 k-tile is 16 dwords -> offset kt*16, not
//     kt*8 (k-ranges overlapped; absmax 0.219). Fixed. Structure unchanged:
//     block = 16 nodes; 4 waves aggregate 4 nodes each into a 16x128 bf16
//     LDS tile (272B stride), then run the 16x128 @ 128xOUT MFMA from LDS.
// CSR build: two-level LDS counting sort (R7, no global atomics).
// NOTE: assumes n <= 65536 (problem fixes N=50000).
// ---------------------------------------------------------------------------

typedef __attribute__((ext_vector_type(8))) short short8v;
typedef __attribute__((ext_vector_type(4))) float f32x4;

#define NPART 256   // coarse partitions (blocks) in PA/PA2

static __device__ __forceinline__ ushort f2bf(float f) {
    __hip_bfloat16 h = __float2bfloat16(f);   // RNE
    return *reinterpret_cast<ushort*>(&h);
}
static __device__ __forceinline__ float bf_lo(uint u) { return __uint_as_float(u << 16); }
static __device__ __forceinline__ float bf_hi(uint u) { return __uint_as_float(u & 0xffff0000u); }

// ------------------------- GEMM1 body (fp32 sources) -----------------------
static __device__ __forceinline__ void gemm1_body(
    const float* __restrict__ X, const float* __restrict__ W,
    const float* __restrict__ bias, ushort* __restrict__ Y, int n,
    int wid, int lane) {
    int r0 = wid * 16;
    if (r0 >= n) return;
    int arow = r0 + (lane & 15);
    if (arow >= n) arow = n - 1;
    int kb = lane >> 4;
    int c  = lane & 15;

    f32x4 acc[8];
#pragma unroll
    for (int ct = 0; ct < 8; ++ct) acc[ct] = (f32x4)(0.f);

#pragma unroll
    for (int kt = 0; kt < 4; ++kt) {
        const float* ap = &X[(size_t)arow * 128 + kt * 32 + kb * 8];
        float4 a0 = *(const float4*)ap;
        float4 a1 = *(const float4*)(ap + 4);
        union { short8v v; ushort u[8]; } av;
        av.u[0] = f2bf(a0.x); av.u[1] = f2bf(a0.y);
        av.u[2] = f2bf(a0.z); av.u[3] = f2bf(a0.w);
        av.u[4] = f2bf(a1.x); av.u[5] = f2bf(a1.y);
        av.u[6] = f2bf(a1.z); av.u[7] = f2bf(a1.w);
#pragma unroll
        for (int ct = 0; ct < 8; ++ct) {
            union { short8v v; ushort u[8]; } bv;
#pragma unroll
            for (int j = 0; j < 8; ++j)
                bv.u[j] = f2bf(W[(size_t)(kt * 32 + kb * 8 + j) * 128 + ct * 16 + c]);
            acc[ct] = __builtin_amdgcn_mfma_f32_16x16x32_bf16(av.v, bv.v, acc[ct], 0, 0, 0);
        }
    }

    int rg = lane >> 4;
#pragma unroll
    for (int ct = 0; ct < 8; ++ct) {
        float bvs = bias[ct * 16 + c];
#pragma unroll
        for (int j = 0; j < 4; ++j) {
            int r = r0 + rg * 4 + j;
            if (r < n) Y[(size_t)r * 128 + ct * 16 + c] = f2bf(acc[ct][j] + bvs);
        }
    }
}

// -------- fused PA: coarse LDS hist (NPART blocks) | gemm1 | repack --------
__global__ __launch_bounds__(256) void fused_pa(
    const int* __restrict__ col, int* __restrict__ Gmat,
    const float* __restrict__ x, const float* __restrict__ W1,
    const float* __restrict__ b1, ushort* __restrict__ hbuf,
    const float* __restrict__ W2, ushort* __restrict__ Wf2,
    const float* __restrict__ W3, ushort* __restrict__ Wf3,
    int n, int E, int NBKT, int ECH, int GB) {
    __shared__ uint hist[1024];
    int b = blockIdx.x, t = threadIdx.x;
    if (b < NPART) {
        for (int i = t; i < NBKT; i += 256) hist[i] = 0;
        __syncthreads();
        int e0 = b * ECH, e1 = min(e0 + ECH, E);
        for (int e = e0 + t; e < e1; e += 256)
            atomicAdd(&hist[col[e] >> 6], 1u);
        __syncthreads();
        for (int i = t; i < NBKT; i += 256)
            Gmat[i * NPART + b] = (int)hist[i];
        return;
    }
    b -= NPART;
    if (b < GB) {
        int wid = (b * 256 + t) >> 6;
        gemm1_body(x, W1, b1, hbuf, n, wid, t & 63);
        return;
    }
    b -= GB;
    // repack: W2 blocks [0,8), W3 blocks [8,12)
    const float* W; ushort* Wf; int OUT; int tid;
    if (b < 8) { W = W2; Wf = Wf2; OUT = 128; tid = b * 256 + t; }
    else       { W = W3; Wf = Wf3; OUT = 64;  tid = (b - 8) * 256 + t; }
    int CT = OUT >> 4;
    int total = 4 * CT * 64;
    if (tid >= total) return;
    int kt   = tid / (CT * 64);
    int rem  = tid % (CT * 64);
    int ct   = rem >> 6;
    int lane = rem & 63;
    int c  = lane & 15;
    int kb = lane >> 4;
    ushort tmp[8];
#pragma unroll
    for (int j = 0; j < 8; ++j)
        tmp[j] = f2bf(W[(kt * 32 + kb * 8 + j) * OUT + ct * 16 + c]);
    uint4 o;
    o.x = ((uint)tmp[1] << 16) | tmp[0];
    o.y = ((uint)tmp[3] << 16) | tmp[2];
    o.z = ((uint)tmp[5] << 16) | tmp[4];
    o.w = ((uint)tmp[7] << 16) | tmp[6];
    ((uint4*)Wf)[tid] = o;
}

// ----------------- scan of flat Gmat (M = NBKT*NPART entries) --------------
__global__ void scanA_partial(const int* __restrict__ g, int* __restrict__ bsum, int M) {
    __shared__ int lds[256];
    int i = blockIdx.x * 256 + threadIdx.x;
    int v = (i < M) ? g[i] : 0;
    lds[threadIdx.x] = v;
    __syncthreads();
    for (int s = 128; s > 0; s >>= 1) {
        if (threadIdx.x < s) lds[threadIdx.x] += lds[threadIdx.x + s];
        __syncthreads();
    }
    if (threadIdx.x == 0) bsum[blockIdx.x] = lds[0];
}

// single block; nb <= 1024; exclusive scan in place
__global__ void scan_bsums_big(int* __restrict__ bsum, int nb) {
    __shared__ int ts[256];
    int t = threadIdx.x;
    int v[4]; int s = 0;
#pragma unroll
    for (int j = 0; j < 4; ++j) {
        int i = t * 4 + j;
        v[j] = (i < nb) ? bsum[i] : 0;
        s += v[j];
    }
    ts[t] = s;
    __syncthreads();
    for (int off = 1; off < 256; off <<= 1) {
        int u = (t >= off) ? ts[t - off] : 0;
        __syncthreads();
        ts[t] += u;
        __syncthreads();
    }
    int run = ts[t] - s;   // exclusive base for this thread's 4
#pragma unroll
    for (int j = 0; j < 4; ++j) {
        int i = t * 4 + j;
        if (i < nb) { int old = v[j]; bsum[i] = run; run += old; }
    }
}

__global__ void scanA_final(int* __restrict__ g, const int* __restrict__ bsum, int M) {
    __shared__ int lds[256];
    int t = threadIdx.x;
    int i = blockIdx.x * 256 + t;
    int v = (i < M) ? g[i] : 0;
    lds[t] = v;
    __syncthreads();
    for (int off = 1; off < 256; off <<= 1) {
        int u = (t >= off) ? lds[t - off] : 0;
        __syncthreads();
        lds[t] += u;
        __syncthreads();
    }
    if (i < M) g[i] = lds[t] - v + bsum[blockIdx.x];   // exclusive
}

// ------------------- PA2: coarse scatter (LDS cursors) ---------------------
__global__ __launch_bounds__(256) void pa2_scatter(
    const int* __restrict__ row, const int* __restrict__ col,
    const int* __restrict__ Gscan, uint* __restrict__ coarse,
    int E, int NBKT, int ECH) {
    __shared__ uint cur[1024];
    int p = blockIdx.x, t = threadIdx.x;
    for (int i = t; i < NBKT; i += 256) cur[i] = (uint)Gscan[i * NPART + p];
    __syncthreads();
    int e0 = p * ECH, e1 = min(e0 + ECH, E);
    for (int e = e0 + t; e < e1; e += 256) {
        int d = col[e];
        uint slot = atomicAdd(&cur[d >> 6], 1u);
        coarse[slot] = ((uint)(d & 63) << 16) | (uint)(row[e] & 0xFFFF);
    }
}

// ---------------- PB: per-bucket fine CSR (64 nodes/bucket) ----------------
__global__ __launch_bounds__(256) void pb_fine(
    const uint* __restrict__ coarse, const int* __restrict__ Gscan,
    int* __restrict__ cnt, int* __restrict__ start,
    ushort* __restrict__ srclist16, int n, int E, int NBKT) {
    __shared__ uint c64[64];
    int b = blockIdx.x, t = threadIdx.x;
    int lo = Gscan[b * NPART];
    int hi = (b + 1 < NBKT) ? Gscan[(b + 1) * NPART] : E;
    if (t < 64) c64[t] = 0;
    __syncthreads();
    for (int i = lo + t; i < hi; i += 256)
        atomicAdd(&c64[coarse[i] >> 16], 1u);
    __syncthreads();
    if (t < 64) {
        uint v = c64[t];
        uint x = v;
#pragma unroll
        for (int off = 1; off < 64; off <<= 1) {
            uint u = __shfl_up(x, off);
            if (t >= off) x += u;
        }
        uint excl = x - v;
        int node = b * 64 + t;
        if (node < n) { cnt[node] = (int)v; start[node] = lo + (int)excl; }
        c64[t] = excl;   // becomes intra-bucket cursor
    }
    __syncthreads();
    for (int i = lo + t; i < hi; i += 256) {
        uint u  = coarse[i];
        uint dl = u >> 16;
        uint slot = atomicAdd(&c64[dl], 1u);
        srclist16[lo + slot] = (ushort)u;
    }
}

// ------------------- gather-mean of one node (128-wide) --------------------
static __device__ __forceinline__ void agg_node128(
    const uint* __restrict__ h32, const ushort* __restrict__ srclist16,
    int s0, int c, int lane, float& ax, float& ay) {
    ax = 0.f; ay = 0.f;
    for (int base = 0; base < c; base += 64) {
        int m = c - base;
        if (m > 64) m = 64;
        int idx = (int)srclist16[s0 + base + (lane < m ? lane : 0)];
        int e = 0;
        for (; e + 8 <= m; e += 8) {
            int i0 = __shfl(idx, e + 0), i1 = __shfl(idx, e + 1);
            int i2 = __shfl(idx, e + 2), i3 = __shfl(idx, e + 3);
            int i4 = __shfl(idx, e + 4), i5 = __shfl(idx, e + 5);
            int i6 = __shfl(idx, e + 6), i7 = __shfl(idx, e + 7);
            uint u0 = h32[(size_t)i0 * 64 + lane];
            uint u1 = h32[(size_t)i1 * 64 + lane];
            uint u2 = h32[(size_t)i2 * 64 + lane];
            uint u3 = h32[(size_t)i3 * 64 + lane];
            uint u4 = h32[(size_t)i4 * 64 + lane];
            uint u5 = h32[(size_t)i5 * 64 + lane];
            uint u6 = h32[(size_t)i6 * 64 + lane];
            uint u7 = h32[(size_t)i7 * 64 + lane];
            ax += ((bf_lo(u0) + bf_lo(u1)) + (bf_lo(u2) + bf_lo(u3))) +
                  ((bf_lo(u4) + bf_lo(u5)) + (bf_lo(u6) + bf_lo(u7)));
            ay += ((bf_hi(u0) + bf_hi(u1)) + (bf_hi(u2) + bf_hi(u3))) +
                  ((bf_hi(u4) + bf_hi(u5)) + (bf_hi(u6) + bf_hi(u7)));
        }
        for (; e + 4 <= m; e += 4) {
            int i0 = __shfl(idx, e + 0), i1 = __shfl(idx, e + 1);
            int i2 = __shfl(idx, e + 2), i3 = __shfl(idx, e + 3);
            uint u0 = h32[(size_t)i0 * 64 + lane];
            uint u1 = h32[(size_t)i1 * 64 + lane];
            uint u2 = h32[(size_t)i2 * 64 + lane];
            uint u3 = h32[(size_t)i3 * 64 + lane];
            ax += (bf_lo(u0) + bf_lo(u1)) + (bf_lo(u2) + bf_lo(u3));
            ay += (bf_hi(u0) + bf_hi(u1)) + (bf_hi(u2) + bf_hi(u3));
        }
        for (; e < m; ++e) {
            int i0 = __shfl(idx, e);
            uint u0 = h32[(size_t)i0 * 64 + lane];
            ax += bf_lo(u0);
            ay += bf_hi(u0);
        }
    }
}

// ------------- fused: agg(128-wide, relu) + gemm(128 x OUT) ----------------
// Block = 16 nodes. 4 waves aggregate 4 nodes each into a 16x128 bf16 LDS
// tile (stride 68 dwords = 272B, 16B-aligned frag reads), then run the MFMA.
template <int OUT>
__global__ __launch_bounds__(256) void fused_agg_gemm(
    const ushort* __restrict__ h, const int* __restrict__ start,
    const int* __restrict__ cnt, const ushort* __restrict__ srclist16,
    const ushort* __restrict__ Wf, const float* __restrict__ bias,
    ushort* __restrict__ Y, int n) {
    constexpr int CT  = OUT / 16;
    constexpr int CTW = CT / 4;        // col-tiles per wave (128->2, 64->1)
    __shared__ uint tile[16 * 68];
    int t = threadIdx.x;
    int wave = t >> 6, lane = t & 63;
    int base = blockIdx.x * 16;
    if (base >= n) return;
    const uint* h32 = (const uint*)h;

    // ---- aggregation phase: wave aggregates rows wave*4 .. wave*4+3 ----
#pragma unroll
    for (int q = 0; q < 4; ++q) {
        int r = wave * 4 + q;
        int node = base + r;
        uint pk = 0;
        if (node < n) {
            int s0 = start[node], c = cnt[node];
            float ax, ay;
            agg_node128(h32, srclist16, s0, c, lane, ax, ay);
            float rx, ry;
            if (c > 0) {
                float inv = 1.f / (float)c;
                rx = ax * inv; ry = ay * inv;
            } else {
                uint u = h32[(size_t)node * 64 + lane];
                rx = bf_lo(u); ry = bf_hi(u);
            }
            rx = fmaxf(rx, 0.f); ry = fmaxf(ry, 0.f);   // relu
            pk = ((uint)f2bf(ry) << 16) | f2bf(rx);
        }
        tile[r * 68 + lane] = pk;
    }
    __syncthreads();

    // ---- gemm phase: 16x128 @ 128xOUT ----
    int ar = lane & 15;
    int kb = lane >> 4;
    f32x4 acc[CTW];
#pragma unroll
    for (int j = 0; j < CTW; ++j) acc[j] = (f32x4)(0.f);

#pragma unroll
    for (int kt = 0; kt < 4; ++kt) {
        // k-tile = 32 bf16 = 16 dwords -> kt*16; kb sub-block = 8 bf16 = 4 dwords
        uint4 a4 = *(const uint4*)&tile[ar * 68 + kt * 16 + kb * 4];
        short8v a = *(const short8v*)&a4;
#pragma unroll
        for (int j = 0; j < CTW; ++j) {
            int ct = wave * CTW + j;
            short8v b = *(const short8v*)&Wf[(size_t)((kt * CT + ct) * 64 + lane) * 8];
            acc[j] = __builtin_amdgcn_mfma_f32_16x16x32_bf16(a, b, acc[j], 0, 0, 0);
        }
    }

    int c16 = lane & 15, rg = lane >> 4;
#pragma unroll
    for (int j = 0; j < CTW; ++j) {
        int ct = wave * CTW + j;
        float bv = bias[ct * 16 + c16];
#pragma unroll
        for (int jj = 0; jj < 4; ++jj) {
            int r = base + rg * 4 + jj;
            if (r < n) Y[(size_t)r * OUT + ct * 16 + c16] = f2bf(acc[j][jj] + bv);
        }
    }
}

// D=64 final layer: lane owns 1 bf16; fused log_softmax; fp32 output.
__global__ __launch_bounds__(256) void agg64_lsm_bf16(
    const ushort* __restrict__ h, const int* __restrict__ start,
    const int* __restrict__ cnt, const ushort* __restrict__ srclist16,
    float* __restrict__ out, int n) {
    int wid  = (blockIdx.x * blockDim.x + threadIdx.x) >> 6;
    int lane = threadIdx.x & 63;
    if (wid >= n) return;
    int s0 = start[wid];
    int c  = cnt[wid];
    float a = 0.f;
    for (int base = 0; base < c; base += 64) {
        int m = c - base;
        if (m > 64) m = 64;
        int idx = (int)srclist16[s0 + base + (lane < m ? lane : 0)];
        int e = 0;
        for (; e + 8 <= m; e += 8) {
            int i0 = __shfl(idx, e + 0), i1 = __shfl(idx, e + 1);
            int i2 = __shfl(idx, e + 2), i3 = __shfl(idx, e + 3);
            int i4 = __shfl(idx, e + 4), i5 = __shfl(idx, e + 5);
            int i6 = __shfl(idx, e + 6), i7 = __shfl(idx, e + 7);
            float v0 = __uint_as_float((uint)h[(size_t)i0 * 64 + lane] << 16);
            float v1 = __uint_as_float((uint)h[(size_t)i1 * 64 + lane] << 16);
            float v2 = __uint_as_float((uint)h[(size_t)i2 * 64 + lane] << 16);
            float v3 = __uint_as_float((uint)h[(size_t)i3 * 64 + lane] << 16);
            float v4 = __uint_as_float((uint)h[(size_t)i4 * 64 + lane] << 16);
            float v5 = __uint_as_float((uint)h[(size_t)i5 * 64 + lane] << 16);
            float v6 = __uint_as_float((uint)h[(size_t)i6 * 64 + lane] << 16);
            float v7 = __uint_as_float((uint)h[(size_t)i7 * 64 + lane] << 16);
            a += ((v0 + v1) + (v2 + v3)) + ((v4 + v5) + (v6 + v7));
        }
        for (; e < m; ++e) {
            int i0 = __shfl(idx, e);
            a += __uint_as_float((uint)h[(size_t)i0 * 64 + lane] << 16);
        }
    }
    float v = (c > 0) ? a / (float)c
                      : __uint_as_float((uint)h[(size_t)wid * 64 + lane] << 16);

    float m = v;
#pragma unroll
    for (int off = 32; off > 0; off >>= 1) m = fmaxf(m, __shfl_xor(m, off));
    float ex = __expf(v - m);
    float s = ex;
#pragma unroll
    for (int off = 32; off > 0; off >>= 1) s += __shfl_xor(s, off);
    out[(size_t)wid * 64 + lane] = v - m - __logf(s);
}

// ---------------------------------------------------------------------------
extern "C" void kernel_launch(void* const* d_in, const int* in_sizes, int n_in,
                              void* d_out, int out_size, void* d_ws, size_t ws_size,
                              hipStream_t stream) {
    const float* x  = (const float*)d_in[0];
    const int*   ei = (const int*)d_in[1];
    const float* W1 = (const float*)d_in[2];
    const float* b1 = (const float*)d_in[3];
    const float* W2 = (const float*)d_in[4];
    const float* b2 = (const float*)d_in[5];
    const float* W3 = (const float*)d_in[6];
    const float* b3 = (const float*)d_in[7];
    float* out = (float*)d_out;

    const int n = in_sizes[0] / 128;
    const int E = in_sizes[1] / 2;
    const int* row = ei;        // edge_index[0]
    const int* col = ei + E;    // edge_index[1]

    char* ws = (char*)d_ws;
    size_t off = 0;
    auto carve = [&](size_t bytes) {
        char* p = ws + off;
        off = (off + bytes + 255) & ~(size_t)255;
        return p;
    };
    ushort* hbuf      = (ushort*)carve((size_t)n * 128 * 2);   // gemm1 out; later gemm3 out (n x 64)
    ushort* abuf      = (ushort*)carve((size_t)n * 128 * 2);   // gemm2 out
    ushort* Wf2       = (ushort*)carve(4 * 8 * 64 * 8 * 2);
    ushort* Wf3       = (ushort*)carve(4 * 4 * 64 * 8 * 2);
    const int NBKT    = (n + 63) / 64;                         // <= 1024
    int*    Gmat      = (int*)carve((size_t)NBKT * NPART * sizeof(int));
    uint*   coarse    = (uint*)carve((size_t)E * sizeof(uint));
    int*    cnt       = (int*)carve((size_t)n * sizeof(int));
    int*    start     = (int*)carve((size_t)n * sizeof(int));
    ushort* srclist16 = (ushort*)carve((size_t)E * 2);
    int*    bsum      = (int*)carve(4096);

    const int ECH   = (E + NPART - 1) / NPART;
    const int M     = NBKT * NPART;              // flat Gmat entries
    const int MB    = (M + 255) / 256;
    const int nwave = (n + 15) / 16;
    const int GB    = (nwave + 3) / 4;           // gemm1 blocks (4 waves/block)
    const int FB    = (n + 15) / 16;             // fused agg+gemm blocks (16 nodes)
    const int agrid = (n + 3) / 4;               // 1 node/wave

    // CSR build (no global atomics) + gemm1 + weight repacks
    fused_pa<<<NPART + GB + 12, 256, 0, stream>>>(col, Gmat, x, W1, b1, hbuf,
                                                  W2, Wf2, W3, Wf3,
                                                  n, E, NBKT, ECH, GB);
    scanA_partial<<<MB, 256, 0, stream>>>(Gmat, bsum, M);
    scan_bsums_big<<<1, 256, 0, stream>>>(bsum, MB);
    scanA_final<<<MB, 256, 0, stream>>>(Gmat, bsum, M);
    pa2_scatter<<<NPART, 256, 0, stream>>>(row, col, Gmat, coarse, E, NBKT, ECH);
    pb_fine<<<NBKT, 256, 0, stream>>>(coarse, Gmat, cnt, start, srclist16, n, E, NBKT);

    // layer boundaries fused: [agg1+gemm2], [agg2+gemm3], agg3+logsoftmax
    fused_agg_gemm<128><<<FB, 256, 0, stream>>>(hbuf, start, cnt, srclist16,
                                                Wf2, b2, abuf, n);
    fused_agg_gemm<64><<<FB, 256, 0, stream>>>(abuf, start, cnt, srclist16,
                                               Wf3, b3, hbuf, n);
    agg64_lsm_bf16<<<agrid, 256, 0, stream>>>(hbuf, start, cnt, srclist16, out, n);
}